// Round 1
// baseline (1894.992 us; speedup 1.0000x reference)
//
#include <hip/hip_runtime.h>
#include <math.h>

#define N_NODES 100000
#define NREL 2
#define IN_DIM 128
#define HID 128
#define OUT_DIM 64
#define BATCH_MAX 4096

// ---------------- workspace layout (bytes) ----------------
// agg0 region is reused for agg1 + x2 after gemm1 consumes agg0.
static const size_t SZ_AGG0 = (size_t)NREL * N_NODES * HID * 4;      // 102.4 MB
static const size_t OFF_AGG0 = 0;
static const size_t OFF_X1   = OFF_AGG0 + SZ_AGG0;                   // N*128 f32
static const size_t SZ_X1    = (size_t)N_NODES * HID * 4;
static const size_t OFF_CNT  = OFF_X1 + SZ_X1;                       // N*2 int
static const size_t SZ_CNT   = (size_t)N_NODES * NREL * 4;
static const size_t OFF_MARK = OFF_CNT + SZ_CNT;                     // N int
static const size_t SZ_MARK  = (size_t)N_NODES * 4;
static const size_t OFF_W0   = OFF_MARK + SZ_MARK;                   // 384*128 f32
static const size_t SZ_W0    = (size_t)384 * 128 * 4;
static const size_t OFF_W1   = OFF_W0 + SZ_W0;                       // 384*64 f32
static const size_t SZ_W1    = (size_t)384 * 64 * 4;
// overlapped into agg0 region (agg0 dead after gemm1):
static const size_t OFF_AGG1 = 0;                                    // 2*4096*128 f32
static const size_t SZ_AGG1  = (size_t)NREL * BATCH_MAX * HID * 4;
static const size_t OFF_X2   = OFF_AGG1 + SZ_AGG1;                   // 4096*64 f32

// ---------------- weight stacking ----------------
// Wst0[384][128]: rows 0..127 = W[r=0], 128..255 = W[r=1], 256..383 = root0
__global__ void build_w0_kernel(const float* __restrict__ basis, const float* __restrict__ comp,
                                const float* __restrict__ root, float* __restrict__ Wst) {
    int idx = blockIdx.x * blockDim.x + threadIdx.x;
    if (idx >= 384 * 128) return;
    int k = idx >> 7, o = idx & 127;
    float v;
    if (k < 256) {
        int r = k >> 7;  // 0 or 1
        int i = k & 127;
        v = comp[r * 2 + 0] * basis[(size_t)(0 * 128 + i) * 128 + o]
          + comp[r * 2 + 1] * basis[(size_t)(1 * 128 + i) * 128 + o];
    } else {
        v = root[(size_t)(k - 256) * 128 + o];
    }
    Wst[idx] = v;
}

__global__ void build_w1_kernel(const float* __restrict__ basis, const float* __restrict__ comp,
                                const float* __restrict__ root, float* __restrict__ Wst) {
    int idx = blockIdx.x * blockDim.x + threadIdx.x;
    if (idx >= 384 * 64) return;
    int k = idx / 64, o = idx % 64;
    float v;
    if (k < 256) {
        int r = k >> 7;
        int i = k & 127;
        v = comp[r * 2 + 0] * basis[(size_t)(0 * 128 + i) * 64 + o]
          + comp[r * 2 + 1] * basis[(size_t)(1 * 128 + i) * 64 + o];
    } else {
        v = root[(size_t)(k - 256) * 64 + o];
    }
    Wst[idx] = v;
}

// ---------------- mark selected nodes ----------------
__global__ void mark_kernel(const int* __restrict__ ni, int* __restrict__ mark, int B) {
    int i = blockIdx.x * blockDim.x + threadIdx.x;
    if (i < B) atomicMax(&mark[ni[i]], i);
}

// ---------------- layer-0 edge scatter (+ degree counts) ----------------
// one 64-lane wave per edge; 2 floats per lane
__global__ void scatter0_kernel(const int* __restrict__ src, const int* __restrict__ dst,
                                const int* __restrict__ etype, const float* __restrict__ x,
                                float* __restrict__ agg, int* __restrict__ cnt, int E) {
    long long g = (long long)blockIdx.x * blockDim.x + threadIdx.x;
    int e = (int)(g >> 6);
    int lane = (int)(g & 63);
    if (e >= E) return;
    int s = src[e], d = dst[e], t = etype[e];
    if (lane == 0) atomicAdd(&cnt[d * 2 + t], 1);
    const float2 v = *(const float2*)(x + (size_t)s * 128 + lane * 2);
    float* base = agg + ((size_t)t * N_NODES + d) * 128 + lane * 2;
    atomicAdd(base, v.x);
    atomicAdd(base + 1, v.y);
}

// ---------------- layer-1 edge scatter (marked dst only) ----------------
__global__ void scatter1_kernel(const int* __restrict__ src, const int* __restrict__ dst,
                                const int* __restrict__ etype, const float* __restrict__ x1,
                                const int* __restrict__ mark, float* __restrict__ agg1, int E) {
    long long g = (long long)blockIdx.x * blockDim.x + threadIdx.x;
    int e = (int)(g >> 6);
    int lane = (int)(g & 63);
    if (e >= E) return;
    int d = dst[e];
    int u = mark[d];
    if (u < 0) return;  // wave-uniform: whole wave exits together
    int s = src[e], t = etype[e];
    const float2 v = *(const float2*)(x1 + (size_t)s * 128 + lane * 2);
    float* base = agg1 + ((size_t)t * BATCH_MAX + u) * 128 + lane * 2;
    atomicAdd(base, v.x);
    atomicAdd(base + 1, v.y);
}

// ---------------- gemm1: x1[N][128] = relu(A @ Wst0 + bias0) ----------------
// A[n] = [agg0_r0[n]/c0, agg0_r1[n]/c1, x[n]]  (K = 384)
#define G1_ROWS 16
__global__ __launch_bounds__(128) void gemm1_kernel(const float* __restrict__ agg0,
                                                    const int* __restrict__ cnt,
                                                    const float* __restrict__ x,
                                                    const float* __restrict__ Wst,
                                                    const float* __restrict__ bias,
                                                    float* __restrict__ x1) {
    __shared__ float As[G1_ROWS][384];
    const int o = threadIdx.x;  // 0..127
    const int row0 = blockIdx.x * G1_ROWS;
    for (int idx = threadIdx.x; idx < G1_ROWS * 384; idx += 128) {
        int r = idx / 384, k = idx - r * 384;
        int n = row0 + r;
        float v = 0.f;
        if (n < N_NODES) {
            if (k < 128) {
                int c = cnt[n * 2 + 0];
                v = agg0[(size_t)n * 128 + k] * (c > 0 ? 1.f / (float)c : 0.f);
            } else if (k < 256) {
                int c = cnt[n * 2 + 1];
                v = agg0[((size_t)N_NODES + n) * 128 + (k - 128)] * (c > 0 ? 1.f / (float)c : 0.f);
            } else {
                v = x[(size_t)n * 128 + (k - 256)];
            }
        }
        As[r][k] = v;
    }
    __syncthreads();
    float acc[G1_ROWS];
#pragma unroll
    for (int r = 0; r < G1_ROWS; r++) acc[r] = 0.f;
    for (int k = 0; k < 384; k += 4) {
        float w0 = Wst[(k + 0) * 128 + o];
        float w1 = Wst[(k + 1) * 128 + o];
        float w2 = Wst[(k + 2) * 128 + o];
        float w3 = Wst[(k + 3) * 128 + o];
#pragma unroll
        for (int r = 0; r < G1_ROWS; r++) {
            const float4 a = *(const float4*)&As[r][k];
            acc[r] = fmaf(a.x, w0, acc[r]);
            acc[r] = fmaf(a.y, w1, acc[r]);
            acc[r] = fmaf(a.z, w2, acc[r]);
            acc[r] = fmaf(a.w, w3, acc[r]);
        }
    }
    const float b = bias[o];
    for (int r = 0; r < G1_ROWS; r++) {
        int n = row0 + r;
        if (n < N_NODES) x1[(size_t)n * 128 + o] = fmaxf(acc[r] + b, 0.f);
    }
}

// ---------------- gemm2: x2[B][64] = A @ Wst1 + bias1 (no relu) ----------------
// A[u] = [agg1_r0[u]/c0, agg1_r1[u]/c1, x1[node_u]]  node_u = node_indices[u]
#define G2_ROWS 16
__global__ __launch_bounds__(64) void gemm2_kernel(const float* __restrict__ agg1,
                                                   const int* __restrict__ cnt,
                                                   const float* __restrict__ x1,
                                                   const int* __restrict__ ni,
                                                   const float* __restrict__ Wst,
                                                   const float* __restrict__ bias,
                                                   float* __restrict__ x2, int B) {
    __shared__ float As[G2_ROWS][384];
    const int o = threadIdx.x;  // 0..63
    const int row0 = blockIdx.x * G2_ROWS;
    for (int idx = threadIdx.x; idx < G2_ROWS * 384; idx += 64) {
        int r = idx / 384, k = idx - r * 384;
        int u = row0 + r;
        float v = 0.f;
        if (u < B) {
            int n = ni[u];
            if (k < 128) {
                int c = cnt[n * 2 + 0];
                v = agg1[(size_t)u * 128 + k] * (c > 0 ? 1.f / (float)c : 0.f);
            } else if (k < 256) {
                int c = cnt[n * 2 + 1];
                v = agg1[((size_t)BATCH_MAX + u) * 128 + (k - 128)] * (c > 0 ? 1.f / (float)c : 0.f);
            } else {
                v = x1[(size_t)n * 128 + (k - 256)];
            }
        }
        As[r][k] = v;
    }
    __syncthreads();
    float acc[G2_ROWS];
#pragma unroll
    for (int r = 0; r < G2_ROWS; r++) acc[r] = 0.f;
    for (int k = 0; k < 384; k += 4) {
        float w0 = Wst[(k + 0) * 64 + o];
        float w1 = Wst[(k + 1) * 64 + o];
        float w2 = Wst[(k + 2) * 64 + o];
        float w3 = Wst[(k + 3) * 64 + o];
#pragma unroll
        for (int r = 0; r < G2_ROWS; r++) {
            const float4 a = *(const float4*)&As[r][k];
            acc[r] = fmaf(a.x, w0, acc[r]);
            acc[r] = fmaf(a.y, w1, acc[r]);
            acc[r] = fmaf(a.z, w2, acc[r]);
            acc[r] = fmaf(a.w, w3, acc[r]);
        }
    }
    const float b = bias[o];
    for (int r = 0; r < G2_ROWS; r++) {
        int u = row0 + r;
        if (u < B) x2[(size_t)u * 64 + o] = acc[r] + b;
    }
}

// ---------------- gather + MLP head ----------------
// one wave (64 threads) per batch row
__global__ __launch_bounds__(64) void mlp_kernel(const int* __restrict__ ni, const int* __restrict__ mark,
                                                 const float* __restrict__ x2,
                                                 const float* __restrict__ W1, const float* __restrict__ b1,
                                                 const float* __restrict__ g1, const float* __restrict__ be1,
                                                 const float* __restrict__ W2, const float* __restrict__ b2,
                                                 const float* __restrict__ g2, const float* __restrict__ be2,
                                                 const float* __restrict__ W3, const float* __restrict__ b3,
                                                 float* __restrict__ outExpert, float* __restrict__ outProb,
                                                 int B) {
    int i = blockIdx.x;
    if (i >= B) return;
    int t = threadIdx.x;   // 0..63
    int tt = t & 31;
    int node = ni[i];
    int u = mark[node];    // representative slot holding identical row
    float e = x2[(size_t)u * 64 + t];
    outExpert[(size_t)i * 64 + t] = e;

    // fc1: y[t] = sum_k e_k * W1[k][t] + b1[t]
    float y = b1[t];
#pragma unroll
    for (int k = 0; k < 64; k++) y = fmaf(__shfl(e, k), W1[k * 64 + t], y);
    // LN over 64
    float s = y;
    for (int off = 32; off; off >>= 1) s += __shfl_xor(s, off);
    float m = s * (1.f / 64.f);
    float d = y - m;
    float vs = d * d;
    for (int off = 32; off; off >>= 1) vs += __shfl_xor(vs, off);
    float h1 = fmaxf(fmaf(g1[t] * d, rsqrtf(vs * (1.f / 64.f) + 1e-5f), be1[t]), 0.f);

    // fc2 (32-wide, duplicated across wave halves)
    float y2 = b2[tt];
#pragma unroll
    for (int k = 0; k < 64; k++) y2 = fmaf(__shfl(h1, k), W2[k * 32 + tt], y2);
    // LN over 32 (offsets <32 stay within each half)
    float s2 = y2;
    for (int off = 16; off; off >>= 1) s2 += __shfl_xor(s2, off);
    float m2 = s2 * (1.f / 32.f);
    float d2 = y2 - m2;
    float v2 = d2 * d2;
    for (int off = 16; off; off >>= 1) v2 += __shfl_xor(v2, off);
    float h2 = fmaxf(fmaf(g2[tt] * d2, rsqrtf(v2 * (1.f / 32.f) + 1e-5f), be2[tt]), 0.f);

    // fc3 -> sigmoid
    float p = h2 * W3[tt];
    for (int off = 16; off; off >>= 1) p += __shfl_xor(p, off);
    if (t == 0) outProb[i] = 1.f / (1.f + expf(-(p + b3[0])));
}

extern "C" void kernel_launch(void* const* d_in, const int* in_sizes, int n_in,
                              void* d_out, int out_size, void* d_ws, size_t ws_size,
                              hipStream_t stream) {
    const int*   node_indices = (const int*)d_in[0];
    const int*   edge_index   = (const int*)d_in[1];
    const int*   edge_type    = (const int*)d_in[2];
    const float* x_feat       = (const float*)d_in[3];
    const float* basis0       = (const float*)d_in[4];
    const float* comp0        = (const float*)d_in[5];
    const float* root0        = (const float*)d_in[6];
    const float* bias0        = (const float*)d_in[7];
    const float* basis1       = (const float*)d_in[8];
    const float* comp1        = (const float*)d_in[9];
    const float* root1        = (const float*)d_in[10];
    const float* bias1        = (const float*)d_in[11];
    const float* W1 = (const float*)d_in[12];
    const float* b1 = (const float*)d_in[13];
    const float* g1 = (const float*)d_in[14];
    const float* be1 = (const float*)d_in[15];
    const float* W2 = (const float*)d_in[16];
    const float* b2 = (const float*)d_in[17];
    const float* g2 = (const float*)d_in[18];
    const float* be2 = (const float*)d_in[19];
    const float* W3 = (const float*)d_in[20];
    const float* b3 = (const float*)d_in[21];

    const int B = in_sizes[0];
    const int E = in_sizes[1] / 2;
    const int* src = edge_index;
    const int* dst = edge_index + E;

    char* ws = (char*)d_ws;
    float* agg0 = (float*)(ws + OFF_AGG0);
    float* x1   = (float*)(ws + OFF_X1);
    int*   cnt  = (int*)(ws + OFF_CNT);
    int*   mark = (int*)(ws + OFF_MARK);
    float* Wst0 = (float*)(ws + OFF_W0);
    float* Wst1 = (float*)(ws + OFF_W1);
    float* agg1 = (float*)(ws + OFF_AGG1);
    float* x2   = (float*)(ws + OFF_X2);

    float* outExpert = (float*)d_out;
    float* outProb   = (float*)d_out + (size_t)B * 64;

    // init
    hipMemsetAsync(agg0, 0, SZ_AGG0, stream);
    hipMemsetAsync(cnt, 0, SZ_CNT, stream);
    hipMemsetAsync(mark, 0xFF, SZ_MARK, stream);  // -1

    build_w0_kernel<<<(384 * 128 + 255) / 256, 256, 0, stream>>>(basis0, comp0, root0, Wst0);
    build_w1_kernel<<<(384 * 64 + 255) / 256, 256, 0, stream>>>(basis1, comp1, root1, Wst1);
    mark_kernel<<<(B + 255) / 256, 256, 0, stream>>>(node_indices, mark, B);

    // layer 0: edge scatter (+counts), then GEMM
    {
        long long threads = (long long)E * 64;
        int blocks = (int)((threads + 255) / 256);
        scatter0_kernel<<<blocks, 256, 0, stream>>>(src, dst, edge_type, x_feat, agg0, cnt, E);
    }
    gemm1_kernel<<<(N_NODES + G1_ROWS - 1) / G1_ROWS, 128, 0, stream>>>(agg0, cnt, x_feat, Wst0, bias0, x1);

    // layer 1 (only marked destinations)
    hipMemsetAsync(agg1, 0, SZ_AGG1, stream);
    {
        long long threads = (long long)E * 64;
        int blocks = (int)((threads + 255) / 256);
        scatter1_kernel<<<blocks, 256, 0, stream>>>(src, dst, edge_type, x1, mark, agg1, E);
    }
    gemm2_kernel<<<(B + G2_ROWS - 1) / G2_ROWS, 64, 0, stream>>>(agg1, cnt, x1, node_indices, Wst1, bias1, x2, B);

    // head
    mlp_kernel<<<B, 64, 0, stream>>>(node_indices, mark, x2,
                                     W1, b1, g1, be1, W2, b2, g2, be2, W3, b3,
                                     outExpert, outProb, B);
}

// Round 2
// 658.549 us; speedup vs baseline: 2.8775x; 2.8775x over previous
//
#include <hip/hip_runtime.h>
#include <math.h>

#define N_NODES 100000
#define NREL 2
#define BATCH_MAX 4096
#define G1_ROWS 16
#define G2_ROWS 16

// ---------------- weight stacking ----------------
// Wst0[384][128]: rows 0..127 = W[r=0], 128..255 = W[r=1], 256..383 = root0
__global__ void build_w0_kernel(const float* __restrict__ basis, const float* __restrict__ comp,
                                const float* __restrict__ root, float* __restrict__ Wst) {
    int idx = blockIdx.x * blockDim.x + threadIdx.x;
    if (idx >= 384 * 128) return;
    int k = idx >> 7, o = idx & 127;
    float v;
    if (k < 256) {
        int r = k >> 7;
        int i = k & 127;
        v = comp[r * 2 + 0] * basis[(size_t)(0 * 128 + i) * 128 + o]
          + comp[r * 2 + 1] * basis[(size_t)(1 * 128 + i) * 128 + o];
    } else {
        v = root[(size_t)(k - 256) * 128 + o];
    }
    Wst[idx] = v;
}

__global__ void build_w1_kernel(const float* __restrict__ basis, const float* __restrict__ comp,
                                const float* __restrict__ root, float* __restrict__ Wst) {
    int idx = blockIdx.x * blockDim.x + threadIdx.x;
    if (idx >= 384 * 64) return;
    int k = idx / 64, o = idx % 64;
    float v;
    if (k < 256) {
        int r = k >> 7;
        int i = k & 127;
        v = comp[r * 2 + 0] * basis[(size_t)(0 * 128 + i) * 64 + o]
          + comp[r * 2 + 1] * basis[(size_t)(1 * 128 + i) * 64 + o];
    } else {
        v = root[(size_t)(k - 256) * 64 + o];
    }
    Wst[idx] = v;
}

// ---------------- CSR build ----------------
__global__ void hist_kernel(const int* __restrict__ dst, const int* __restrict__ etype,
                            int* __restrict__ cnt, int E) {
    int e = blockIdx.x * blockDim.x + threadIdx.x;
    if (e < E) atomicAdd(&cnt[dst[e] * 2 + etype[e]], 1);
}

__global__ void scan1_kernel(const int* __restrict__ cnt, int* __restrict__ rowptr,
                             int* __restrict__ partial) {
    __shared__ int s[256];
    int n = blockIdx.x * 256 + threadIdx.x;
    int d = 0;
    if (n < N_NODES) d = cnt[n * 2] + cnt[n * 2 + 1];
    s[threadIdx.x] = d;
    __syncthreads();
    for (int off = 1; off < 256; off <<= 1) {
        int v = (threadIdx.x >= off) ? s[threadIdx.x - off] : 0;
        __syncthreads();
        s[threadIdx.x] += v;
        __syncthreads();
    }
    if (n < N_NODES) rowptr[n] = s[threadIdx.x] - d;  // exclusive within block
    if (threadIdx.x == 255) partial[blockIdx.x] = s[255];
}

__global__ void scan2_kernel(int* __restrict__ partial, int nb) {
    if (blockIdx.x == 0 && threadIdx.x == 0) {
        int run = 0;
        for (int b = 0; b < nb; b++) { int t = partial[b]; partial[b] = run; run += t; }
    }
}

__global__ void scan3_kernel(int* __restrict__ rowptr, int* __restrict__ cursor,
                             const int* __restrict__ partial, int E) {
    int n = blockIdx.x * 256 + threadIdx.x;
    if (n < N_NODES) {
        int v = rowptr[n] + partial[blockIdx.x];
        rowptr[n] = v;
        cursor[n] = v;
    }
    if (n == 0) rowptr[N_NODES] = E;
}

__global__ void fill_kernel(const int* __restrict__ src, const int* __restrict__ dst,
                            const int* __restrict__ etype, int* __restrict__ cursor,
                            int* __restrict__ adj, int E) {
    int e = blockIdx.x * blockDim.x + threadIdx.x;
    if (e >= E) return;
    int pos = atomicAdd(&cursor[dst[e]], 1);
    adj[pos] = src[e] | (etype[e] << 20);   // src < 2^20
}

// ---------------- layer 0: fused CSR-gather + GEMM ----------------
// block = 256 threads (4 waves), 16 nodes per block. K=384, out=128.
__global__ __launch_bounds__(256) void layer0_kernel(const int* __restrict__ rowptr,
                                                     const int* __restrict__ adj,
                                                     const int* __restrict__ cnt,
                                                     const float* __restrict__ x,
                                                     const float* __restrict__ Wst,
                                                     const float* __restrict__ bias,
                                                     float* __restrict__ x1) {
    __shared__ float As[G1_ROWS][384];
    const int tid = threadIdx.x;
    const int lane = tid & 63;
    const int w = tid >> 6;               // wave 0..3
    const int n0 = blockIdx.x * G1_ROWS;  // N_NODES % 16 == 0

    // ---- gather phase: wave w handles rows w, w+4, w+8, w+12 ----
    for (int j = 0; j < 4; j++) {
        const int r = w + j * 4;
        const int n = n0 + r;
        float2 a0 = make_float2(0.f, 0.f), a1 = make_float2(0.f, 0.f);
        const int beg = rowptr[n], end = rowptr[n + 1];
        int i = beg;
        for (; i + 1 < end; i += 2) {   // unroll x2: overlap dependent load chains
            const int p0 = adj[i], p1 = adj[i + 1];
            const float2 v0 = *(const float2*)(x + (size_t)(p0 & 0xFFFFF) * 128 + lane * 2);
            const float2 v1 = *(const float2*)(x + (size_t)(p1 & 0xFFFFF) * 128 + lane * 2);
            if (p0 >> 20) { a1.x += v0.x; a1.y += v0.y; } else { a0.x += v0.x; a0.y += v0.y; }
            if (p1 >> 20) { a1.x += v1.x; a1.y += v1.y; } else { a0.x += v1.x; a0.y += v1.y; }
        }
        if (i < end) {
            const int p0 = adj[i];
            const float2 v0 = *(const float2*)(x + (size_t)(p0 & 0xFFFFF) * 128 + lane * 2);
            if (p0 >> 20) { a1.x += v0.x; a1.y += v0.y; } else { a0.x += v0.x; a0.y += v0.y; }
        }
        const int c0 = cnt[n * 2], c1 = cnt[n * 2 + 1];
        const float i0 = c0 > 0 ? 1.f / (float)c0 : 0.f;
        const float i1 = c1 > 0 ? 1.f / (float)c1 : 0.f;
        const float2 xv = *(const float2*)(x + (size_t)n * 128 + lane * 2);
        *(float2*)&As[r][lane * 2]       = make_float2(a0.x * i0, a0.y * i0);
        *(float2*)&As[r][128 + lane * 2] = make_float2(a1.x * i1, a1.y * i1);
        *(float2*)&As[r][256 + lane * 2] = xv;
    }
    __syncthreads();

    // ---- gemm phase: o = tid&127; half-threads take rows 0-7 / 8-15 ----
    const int o = tid & 127;
    const int rh = tid >> 7;
    float acc[8];
#pragma unroll
    for (int q = 0; q < 8; q++) acc[q] = 0.f;
    for (int k = 0; k < 384; k += 4) {
        const float w0 = Wst[(k + 0) * 128 + o];
        const float w1 = Wst[(k + 1) * 128 + o];
        const float w2 = Wst[(k + 2) * 128 + o];
        const float w3 = Wst[(k + 3) * 128 + o];
#pragma unroll
        for (int q = 0; q < 8; q++) {
            const float4 a = *(const float4*)&As[rh * 8 + q][k];
            acc[q] = fmaf(a.x, w0, acc[q]);
            acc[q] = fmaf(a.y, w1, acc[q]);
            acc[q] = fmaf(a.z, w2, acc[q]);
            acc[q] = fmaf(a.w, w3, acc[q]);
        }
    }
    const float b = bias[o];
#pragma unroll
    for (int q = 0; q < 8; q++) {
        const int n = n0 + rh * 8 + q;
        x1[(size_t)n * 128 + o] = fmaxf(acc[q] + b, 0.f);
    }
}

// ---------------- layer 1 gather (batch slots only) ----------------
__global__ void gather1_kernel(const int* __restrict__ ni, const int* __restrict__ rowptr,
                               const int* __restrict__ adj, const int* __restrict__ cnt,
                               const float* __restrict__ x1, float* __restrict__ agg1, int B) {
    int g = blockIdx.x * blockDim.x + threadIdx.x;
    int u = g >> 6, lane = g & 63;
    if (u >= B) return;
    int n = ni[u];
    float2 a0 = make_float2(0.f, 0.f), a1 = make_float2(0.f, 0.f);
    const int beg = rowptr[n], end = rowptr[n + 1];
    int i = beg;
    for (; i + 1 < end; i += 2) {
        const int p0 = adj[i], p1 = adj[i + 1];
        const float2 v0 = *(const float2*)(x1 + (size_t)(p0 & 0xFFFFF) * 128 + lane * 2);
        const float2 v1 = *(const float2*)(x1 + (size_t)(p1 & 0xFFFFF) * 128 + lane * 2);
        if (p0 >> 20) { a1.x += v0.x; a1.y += v0.y; } else { a0.x += v0.x; a0.y += v0.y; }
        if (p1 >> 20) { a1.x += v1.x; a1.y += v1.y; } else { a0.x += v1.x; a0.y += v1.y; }
    }
    if (i < end) {
        const int p0 = adj[i];
        const float2 v0 = *(const float2*)(x1 + (size_t)(p0 & 0xFFFFF) * 128 + lane * 2);
        if (p0 >> 20) { a1.x += v0.x; a1.y += v0.y; } else { a0.x += v0.x; a0.y += v0.y; }
    }
    const int c0 = cnt[n * 2], c1 = cnt[n * 2 + 1];
    const float i0 = c0 > 0 ? 1.f / (float)c0 : 0.f;
    const float i1 = c1 > 0 ? 1.f / (float)c1 : 0.f;
    *(float2*)(agg1 + (size_t)u * 128 + lane * 2) = make_float2(a0.x * i0, a0.y * i0);
    *(float2*)(agg1 + ((size_t)BATCH_MAX + u) * 128 + lane * 2) = make_float2(a1.x * i1, a1.y * i1);
}

// ---------------- gemm2: x2[B][64] = A @ Wst1 + bias1 ----------------
// A[u] = [agg1_r0[u], agg1_r1[u], x1[ni[u]]]  (agg1 pre-normalized)
__global__ __launch_bounds__(64) void gemm2_kernel(const float* __restrict__ agg1,
                                                   const float* __restrict__ x1,
                                                   const int* __restrict__ ni,
                                                   const float* __restrict__ Wst,
                                                   const float* __restrict__ bias,
                                                   float* __restrict__ x2, int B) {
    __shared__ float As[G2_ROWS][384];
    const int o = threadIdx.x;  // 0..63
    const int row0 = blockIdx.x * G2_ROWS;
    for (int idx = threadIdx.x; idx < G2_ROWS * 384; idx += 64) {
        int r = idx / 384, k = idx - r * 384;
        int u = row0 + r;
        float v = 0.f;
        if (u < B) {
            if (k < 128) {
                v = agg1[(size_t)u * 128 + k];
            } else if (k < 256) {
                v = agg1[((size_t)BATCH_MAX + u) * 128 + (k - 128)];
            } else {
                int n = ni[u];
                v = x1[(size_t)n * 128 + (k - 256)];
            }
        }
        As[r][k] = v;
    }
    __syncthreads();
    float acc[G2_ROWS];
#pragma unroll
    for (int r = 0; r < G2_ROWS; r++) acc[r] = 0.f;
    for (int k = 0; k < 384; k += 4) {
        const float w0 = Wst[(k + 0) * 64 + o];
        const float w1 = Wst[(k + 1) * 64 + o];
        const float w2 = Wst[(k + 2) * 64 + o];
        const float w3 = Wst[(k + 3) * 64 + o];
#pragma unroll
        for (int r = 0; r < G2_ROWS; r++) {
            const float4 a = *(const float4*)&As[r][k];
            acc[r] = fmaf(a.x, w0, acc[r]);
            acc[r] = fmaf(a.y, w1, acc[r]);
            acc[r] = fmaf(a.z, w2, acc[r]);
            acc[r] = fmaf(a.w, w3, acc[r]);
        }
    }
    const float b = bias[o];
    for (int r = 0; r < G2_ROWS; r++) {
        int u = row0 + r;
        if (u < B) x2[(size_t)u * 64 + o] = acc[r] + b;
    }
}

// ---------------- gather + MLP head ----------------
__global__ __launch_bounds__(64) void mlp_kernel(const float* __restrict__ x2,
                                                 const float* __restrict__ W1, const float* __restrict__ b1,
                                                 const float* __restrict__ g1, const float* __restrict__ be1,
                                                 const float* __restrict__ W2, const float* __restrict__ b2,
                                                 const float* __restrict__ g2, const float* __restrict__ be2,
                                                 const float* __restrict__ W3, const float* __restrict__ b3,
                                                 float* __restrict__ outExpert, float* __restrict__ outProb,
                                                 int B) {
    int i = blockIdx.x;
    if (i >= B) return;
    int t = threadIdx.x;   // 0..63
    int tt = t & 31;
    float e = x2[(size_t)i * 64 + t];
    outExpert[(size_t)i * 64 + t] = e;

    float y = b1[t];
#pragma unroll
    for (int k = 0; k < 64; k++) y = fmaf(__shfl(e, k), W1[k * 64 + t], y);
    float s = y;
    for (int off = 32; off; off >>= 1) s += __shfl_xor(s, off);
    float m = s * (1.f / 64.f);
    float d = y - m;
    float vs = d * d;
    for (int off = 32; off; off >>= 1) vs += __shfl_xor(vs, off);
    float h1 = fmaxf(fmaf(g1[t] * d, rsqrtf(vs * (1.f / 64.f) + 1e-5f), be1[t]), 0.f);

    float y2 = b2[tt];
#pragma unroll
    for (int k = 0; k < 64; k++) y2 = fmaf(__shfl(h1, k), W2[k * 32 + tt], y2);
    float s2 = y2;
    for (int off = 16; off; off >>= 1) s2 += __shfl_xor(s2, off);
    float m2 = s2 * (1.f / 32.f);
    float d2 = y2 - m2;
    float v2 = d2 * d2;
    for (int off = 16; off; off >>= 1) v2 += __shfl_xor(v2, off);
    float h2 = fmaxf(fmaf(g2[tt] * d2, rsqrtf(v2 * (1.f / 32.f) + 1e-5f), be2[tt]), 0.f);

    float p = h2 * W3[tt];
    for (int off = 16; off; off >>= 1) p += __shfl_xor(p, off);
    if (t == 0) outProb[i] = 1.f / (1.f + expf(-(p + b3[0])));
}

extern "C" void kernel_launch(void* const* d_in, const int* in_sizes, int n_in,
                              void* d_out, int out_size, void* d_ws, size_t ws_size,
                              hipStream_t stream) {
    const int*   node_indices = (const int*)d_in[0];
    const int*   edge_index   = (const int*)d_in[1];
    const int*   edge_type    = (const int*)d_in[2];
    const float* x_feat       = (const float*)d_in[3];
    const float* basis0       = (const float*)d_in[4];
    const float* comp0        = (const float*)d_in[5];
    const float* root0        = (const float*)d_in[6];
    const float* bias0        = (const float*)d_in[7];
    const float* basis1       = (const float*)d_in[8];
    const float* comp1        = (const float*)d_in[9];
    const float* root1        = (const float*)d_in[10];
    const float* bias1        = (const float*)d_in[11];
    const float* W1 = (const float*)d_in[12];
    const float* b1 = (const float*)d_in[13];
    const float* g1 = (const float*)d_in[14];
    const float* be1 = (const float*)d_in[15];
    const float* W2 = (const float*)d_in[16];
    const float* b2 = (const float*)d_in[17];
    const float* g2 = (const float*)d_in[18];
    const float* be2 = (const float*)d_in[19];
    const float* W3 = (const float*)d_in[20];
    const float* b3 = (const float*)d_in[21];

    const int B = in_sizes[0];
    const int E = in_sizes[1] / 2;
    const int* src = edge_index;
    const int* dst = edge_index + E;
    const int nb = (N_NODES + 255) / 256;

    // ---- workspace carve-out (256B aligned) ----
    size_t off = 0;
    auto alloc = [&](size_t sz) { size_t o = off; off = (off + sz + 255) & ~(size_t)255; return o; };
    char* ws = (char*)d_ws;
    float* x1     = (float*)(ws + alloc((size_t)N_NODES * 128 * 4));
    int*   cnt    = (int*)  (ws + alloc((size_t)N_NODES * 2 * 4));
    int*   rowptr = (int*)  (ws + alloc((size_t)(N_NODES + 1) * 4));
    int*   cursor = (int*)  (ws + alloc((size_t)N_NODES * 4));
    int*   partial= (int*)  (ws + alloc((size_t)(nb + 1) * 4));
    int*   adj    = (int*)  (ws + alloc((size_t)E * 4));
    float* Wst0   = (float*)(ws + alloc((size_t)384 * 128 * 4));
    float* Wst1   = (float*)(ws + alloc((size_t)384 * 64 * 4));
    float* agg1   = (float*)(ws + alloc((size_t)NREL * BATCH_MAX * 128 * 4));
    float* x2     = (float*)(ws + alloc((size_t)BATCH_MAX * 64 * 4));

    float* outExpert = (float*)d_out;
    float* outProb   = (float*)d_out + (size_t)B * 64;

    hipMemsetAsync(cnt, 0, (size_t)N_NODES * 2 * 4, stream);

    build_w0_kernel<<<(384 * 128 + 255) / 256, 256, 0, stream>>>(basis0, comp0, root0, Wst0);
    build_w1_kernel<<<(384 * 64 + 255) / 256, 256, 0, stream>>>(basis1, comp1, root1, Wst1);

    // ---- CSR build ----
    hist_kernel<<<(E + 255) / 256, 256, 0, stream>>>(dst, edge_type, cnt, E);
    scan1_kernel<<<nb, 256, 0, stream>>>(cnt, rowptr, partial);
    scan2_kernel<<<1, 64, 0, stream>>>(partial, nb);
    scan3_kernel<<<nb, 256, 0, stream>>>(rowptr, cursor, partial, E);
    fill_kernel<<<(E + 255) / 256, 256, 0, stream>>>(src, dst, edge_type, cursor, adj, E);

    // ---- layer 0 (fused gather + GEMM + relu) ----
    layer0_kernel<<<N_NODES / G1_ROWS, 256, 0, stream>>>(rowptr, adj, cnt, x_feat, Wst0, bias0, x1);

    // ---- layer 1 (batch rows only) ----
    gather1_kernel<<<((size_t)B * 64 + 255) / 256, 256, 0, stream>>>(node_indices, rowptr, adj, cnt, x1, agg1, B);
    gemm2_kernel<<<(B + G2_ROWS - 1) / G2_ROWS, 64, 0, stream>>>(agg1, x1, node_indices, Wst1, bias1, x2, B);

    // ---- head ----
    mlp_kernel<<<B, 64, 0, stream>>>(x2, W1, b1, g1, be1, W2, b2, g2, be2, W3, b3,
                                     outExpert, outProb, B);
}

// Round 5
// 419.835 us; speedup vs baseline: 4.5137x; 1.5686x over previous
//
#include <hip/hip_runtime.h>
#include <math.h>

#define N_NODES 100000
#define NREL 2
#define BATCH_MAX 4096
#define G2_ROWS 16

typedef __attribute__((ext_vector_type(8))) short bf16x8;
typedef __attribute__((ext_vector_type(4))) float f32x4;

__device__ inline ushort f2bf(float f) {
    unsigned u = __float_as_uint(f);
    u += 0x7FFF + ((u >> 16) & 1);
    return (ushort)(u >> 16);
}
__device__ inline float bf2f(ushort h) {
    return __uint_as_float(((unsigned)h) << 16);
}

// ---------------- x_feat -> bf16 ----------------
__global__ void tobf16_kernel(const float* __restrict__ x, ushort* __restrict__ xb, int total) {
    int i = (blockIdx.x * blockDim.x + threadIdx.x) * 4;
    if (i >= total) return;
    float4 v = *(const float4*)(x + i);
    uint2 p;
    p.x = ((unsigned)f2bf(v.x)) | (((unsigned)f2bf(v.y)) << 16);
    p.y = ((unsigned)f2bf(v.z)) | (((unsigned)f2bf(v.w)) << 16);
    *(uint2*)(xb + i) = p;
}

// ---------------- weight stacking ----------------
// Wt0b[o][k] (bf16, transposed): k 0..127 = W_r0, 128..255 = W_r1, 256..383 = root0
__global__ void build_w0t_kernel(const float* __restrict__ basis, const float* __restrict__ comp,
                                 const float* __restrict__ root, ushort* __restrict__ Wt) {
    int idx = blockIdx.x * blockDim.x + threadIdx.x;
    if (idx >= 384 * 128) return;
    int k = idx >> 7, o = idx & 127;
    float v;
    if (k < 256) {
        int r = k >> 7;
        int i = k & 127;
        v = comp[r * 2 + 0] * basis[(size_t)(0 * 128 + i) * 128 + o]
          + comp[r * 2 + 1] * basis[(size_t)(1 * 128 + i) * 128 + o];
    } else {
        v = root[(size_t)(k - 256) * 128 + o];
    }
    Wt[(size_t)o * 384 + k] = f2bf(v);
}

// Wst1[384][64] f32 (gemm2 is small; stays VALU f32)
__global__ void build_w1_kernel(const float* __restrict__ basis, const float* __restrict__ comp,
                                const float* __restrict__ root, float* __restrict__ Wst) {
    int idx = blockIdx.x * blockDim.x + threadIdx.x;
    if (idx >= 384 * 64) return;
    int k = idx / 64, o = idx % 64;
    float v;
    if (k < 256) {
        int r = k >> 7;
        int i = k & 127;
        v = comp[r * 2 + 0] * basis[(size_t)(0 * 128 + i) * 64 + o]
          + comp[r * 2 + 1] * basis[(size_t)(1 * 128 + i) * 64 + o];
    } else {
        v = root[(size_t)(k - 256) * 64 + o];
    }
    Wst[idx] = v;
}

// ---------------- CSR build ----------------
__global__ void hist_kernel(const int* __restrict__ dst, const int* __restrict__ etype,
                            int* __restrict__ cnt, int E) {
    int e = blockIdx.x * blockDim.x + threadIdx.x;
    if (e < E) atomicAdd(&cnt[dst[e] * 2 + etype[e]], 1);
}

__global__ void scan1_kernel(const int* __restrict__ cnt, int* __restrict__ rowptr,
                             int* __restrict__ partial) {
    __shared__ int s[256];
    int n = blockIdx.x * 256 + threadIdx.x;
    int d = 0;
    if (n < N_NODES) d = cnt[n * 2] + cnt[n * 2 + 1];
    s[threadIdx.x] = d;
    __syncthreads();
    for (int off = 1; off < 256; off <<= 1) {
        int v = (threadIdx.x >= off) ? s[threadIdx.x - off] : 0;
        __syncthreads();
        s[threadIdx.x] += v;
        __syncthreads();
    }
    if (n < N_NODES) rowptr[n] = s[threadIdx.x] - d;  // exclusive within block
    if (threadIdx.x == 255) partial[blockIdx.x] = s[255];
}

// parallel exclusive scan of block partials (nb <= 512)
__global__ void scan2_kernel(int* __restrict__ partial, int nb) {
    __shared__ int s[512];
    int t = threadIdx.x;
    int v = (t < nb) ? partial[t] : 0;
    s[t] = v;
    __syncthreads();
    for (int off = 1; off < 512; off <<= 1) {
        int u = (t >= off) ? s[t - off] : 0;
        __syncthreads();
        s[t] += u;
        __syncthreads();
    }
    if (t < nb) partial[t] = s[t] - v;
}

__global__ void scan3_kernel(int* __restrict__ rowptr, int* __restrict__ cursor,
                             const int* __restrict__ partial, int E) {
    int n = blockIdx.x * 256 + threadIdx.x;
    if (n < N_NODES) {
        int v = rowptr[n] + partial[blockIdx.x];
        rowptr[n] = v;
        cursor[n] = v;
    }
    if (n == 0) rowptr[N_NODES] = E;
}

__global__ void fill_kernel(const int* __restrict__ src, const int* __restrict__ dst,
                            const int* __restrict__ etype, int* __restrict__ cursor,
                            int* __restrict__ adj, int E) {
    int e = blockIdx.x * blockDim.x + threadIdx.x;
    if (e >= E) return;
    int pos = atomicAdd(&cursor[dst[e]], 1);
    adj[pos] = src[e] | (etype[e] << 20);   // src < 2^20
}

// ---------------- gather0: one wave per node, builds A[N][384] bf16 ----------------
// A[n] = [agg_r0/c0 | agg_r1/c1 | x[n]]
__global__ __launch_bounds__(256) void gather0_kernel(const int* __restrict__ rowptr,
                                                      const int* __restrict__ adj,
                                                      const int* __restrict__ cnt,
                                                      const ushort* __restrict__ xb,
                                                      ushort* __restrict__ A) {
    int g = blockIdx.x * blockDim.x + threadIdx.x;
    int n = g >> 6, lane = g & 63;
    if (n >= N_NODES) return;
    float a0x = 0.f, a0y = 0.f, a1x = 0.f, a1y = 0.f;
    const int beg = rowptr[n], end = rowptr[n + 1];
    int i = beg;
    for (; i + 3 < end; i += 4) {   // 4 edges in flight
        const int p0 = adj[i], p1 = adj[i + 1], p2 = adj[i + 2], p3 = adj[i + 3];
        const unsigned u0 = *(const unsigned*)(xb + (size_t)(p0 & 0xFFFFF) * 128 + lane * 2);
        const unsigned u1 = *(const unsigned*)(xb + (size_t)(p1 & 0xFFFFF) * 128 + lane * 2);
        const unsigned u2 = *(const unsigned*)(xb + (size_t)(p2 & 0xFFFFF) * 128 + lane * 2);
        const unsigned u3 = *(const unsigned*)(xb + (size_t)(p3 & 0xFFFFF) * 128 + lane * 2);
        float lx, ly;
        lx = __uint_as_float(u0 << 16); ly = __uint_as_float(u0 & 0xFFFF0000u);
        if (p0 >> 20) { a1x += lx; a1y += ly; } else { a0x += lx; a0y += ly; }
        lx = __uint_as_float(u1 << 16); ly = __uint_as_float(u1 & 0xFFFF0000u);
        if (p1 >> 20) { a1x += lx; a1y += ly; } else { a0x += lx; a0y += ly; }
        lx = __uint_as_float(u2 << 16); ly = __uint_as_float(u2 & 0xFFFF0000u);
        if (p2 >> 20) { a1x += lx; a1y += ly; } else { a0x += lx; a0y += ly; }
        lx = __uint_as_float(u3 << 16); ly = __uint_as_float(u3 & 0xFFFF0000u);
        if (p3 >> 20) { a1x += lx; a1y += ly; } else { a0x += lx; a0y += ly; }
    }
    for (; i < end; i++) {
        const int p0 = adj[i];
        const unsigned u0 = *(const unsigned*)(xb + (size_t)(p0 & 0xFFFFF) * 128 + lane * 2);
        float lx = __uint_as_float(u0 << 16), ly = __uint_as_float(u0 & 0xFFFF0000u);
        if (p0 >> 20) { a1x += lx; a1y += ly; } else { a0x += lx; a0y += ly; }
    }
    const int c0 = cnt[n * 2], c1 = cnt[n * 2 + 1];
    const float i0 = c0 > 0 ? 1.f / (float)c0 : 0.f;
    const float i1 = c1 > 0 ? 1.f / (float)c1 : 0.f;
    ushort* out = A + (size_t)n * 384 + lane * 2;
    *(unsigned*)(out)       = ((unsigned)f2bf(a0x * i0)) | (((unsigned)f2bf(a0y * i0)) << 16);
    *(unsigned*)(out + 128) = ((unsigned)f2bf(a1x * i1)) | (((unsigned)f2bf(a1y * i1)) << 16);
    *(unsigned*)(out + 256) = *(const unsigned*)(xb + (size_t)n * 128 + lane * 2);
}

// ---------------- gemm0 (MFMA bf16): x1[N][128] = relu(A[N][384] @ W + bias) ----------------
// block 256 thr (4 waves), tile 128 rows x 128 cols, BK=64.
#define BM 128
#define BK 64
__global__ __launch_bounds__(256) void gemm0_kernel(const ushort* __restrict__ A,
                                                    const ushort* __restrict__ Wt,   // [128][384]
                                                    const float* __restrict__ bias,
                                                    ushort* __restrict__ x1) {
    __shared__ ushort As[BM][BK + 8];
    __shared__ ushort Ws[128][BK + 8];
    const int tid = threadIdx.x;
    const int lane = tid & 63;
    const int w = tid >> 6;
    const int row0 = blockIdx.x * BM;

    f32x4 acc[2][8];
#pragma unroll
    for (int t = 0; t < 2; t++)
#pragma unroll
        for (int c = 0; c < 8; c++) acc[t][c] = (f32x4)0.f;

    for (int kc = 0; kc < 384; kc += BK) {
        __syncthreads();
#pragma unroll
        for (int q = 0; q < 4; q++) {
            const int seg = q * 256 + tid;       // 0..1023
            const int row = seg >> 3;            // 0..127
            const int sk = (seg & 7) * 8;
            const int gr = min(row0 + row, N_NODES - 1);
            *(uint4*)&As[row][sk] = *(const uint4*)&A[(size_t)gr * 384 + kc + sk];
            *(uint4*)&Ws[row][sk] = *(const uint4*)&Wt[(size_t)row * 384 + kc + sk];
        }
        __syncthreads();
#pragma unroll
        for (int k2 = 0; k2 < 2; k2++) {
            const int kk = k2 * 32 + (lane >> 4) * 8;
            const bf16x8 af0 = *(const bf16x8*)&As[w * 32 + (lane & 15)][kk];
            const bf16x8 af1 = *(const bf16x8*)&As[w * 32 + 16 + (lane & 15)][kk];
            bf16x8 bf[8];
#pragma unroll
            for (int c = 0; c < 8; c++) bf[c] = *(const bf16x8*)&Ws[c * 16 + (lane & 15)][kk];
#pragma unroll
            for (int c = 0; c < 8; c++) {
                acc[0][c] = __builtin_amdgcn_mfma_f32_16x16x32_bf16(af0, bf[c], acc[0][c], 0, 0, 0);
                acc[1][c] = __builtin_amdgcn_mfma_f32_16x16x32_bf16(af1, bf[c], acc[1][c], 0, 0, 0);
            }
        }
    }

    // D layout: col = lane&15, row = (lane>>4)*4 + j
#pragma unroll
    for (int c = 0; c < 8; c++) {
        const int col = c * 16 + (lane & 15);
        const float b = bias[col];
#pragma unroll
        for (int t = 0; t < 2; t++) {
#pragma unroll
            for (int j = 0; j < 4; j++) {
                const int n = row0 + w * 32 + t * 16 + (lane >> 4) * 4 + j;
                if (n < N_NODES) x1[(size_t)n * 128 + col] = f2bf(fmaxf(acc[t][c][j] + b, 0.f));
            }
        }
    }
}

// ---------------- layer 1 gather (batch slots only) ----------------
__global__ void gather1_kernel(const int* __restrict__ ni, const int* __restrict__ rowptr,
                               const int* __restrict__ adj, const int* __restrict__ cnt,
                               const ushort* __restrict__ x1, float* __restrict__ agg1, int B) {
    int g = blockIdx.x * blockDim.x + threadIdx.x;
    int u = g >> 6, lane = g & 63;
    if (u >= B) return;
    int n = ni[u];
    float a0x = 0.f, a0y = 0.f, a1x = 0.f, a1y = 0.f;
    const int beg = rowptr[n], end = rowptr[n + 1];
    int i = beg;
    for (; i + 1 < end; i += 2) {
        const int p0 = adj[i], p1 = adj[i + 1];
        const unsigned u0 = *(const unsigned*)(x1 + (size_t)(p0 & 0xFFFFF) * 128 + lane * 2);
        const unsigned u1 = *(const unsigned*)(x1 + (size_t)(p1 & 0xFFFFF) * 128 + lane * 2);
        float lx, ly;
        lx = __uint_as_float(u0 << 16); ly = __uint_as_float(u0 & 0xFFFF0000u);
        if (p0 >> 20) { a1x += lx; a1y += ly; } else { a0x += lx; a0y += ly; }
        lx = __uint_as_float(u1 << 16); ly = __uint_as_float(u1 & 0xFFFF0000u);
        if (p1 >> 20) { a1x += lx; a1y += ly; } else { a0x += lx; a0y += ly; }
    }
    if (i < end) {
        const int p0 = adj[i];
        const unsigned u0 = *(const unsigned*)(x1 + (size_t)(p0 & 0xFFFFF) * 128 + lane * 2);
        float lx = __uint_as_float(u0 << 16), ly = __uint_as_float(u0 & 0xFFFF0000u);
        if (p0 >> 20) { a1x += lx; a1y += ly; } else { a0x += lx; a0y += ly; }
    }
    const int c0 = cnt[n * 2], c1 = cnt[n * 2 + 1];
    const float i0 = c0 > 0 ? 1.f / (float)c0 : 0.f;
    const float i1 = c1 > 0 ? 1.f / (float)c1 : 0.f;
    *(float2*)(agg1 + (size_t)u * 128 + lane * 2) = make_float2(a0x * i0, a0y * i0);
    *(float2*)(agg1 + ((size_t)BATCH_MAX + u) * 128 + lane * 2) = make_float2(a1x * i1, a1y * i1);
}

// ---------------- gemm2: x2[B][64] = A @ Wst1 + bias1 ----------------
__global__ __launch_bounds__(64) void gemm2_kernel(const float* __restrict__ agg1,
                                                   const ushort* __restrict__ x1,
                                                   const int* __restrict__ ni,
                                                   const float* __restrict__ Wst,
                                                   const float* __restrict__ bias,
                                                   float* __restrict__ x2, int B) {
    __shared__ float As[G2_ROWS][384];
    const int o = threadIdx.x;  // 0..63
    const int row0 = blockIdx.x * G2_ROWS;
    for (int idx = threadIdx.x; idx < G2_ROWS * 384; idx += 64) {
        int r = idx / 384, k = idx - r * 384;
        int u = row0 + r;
        float v = 0.f;
        if (u < B) {
            if (k < 128) {
                v = agg1[(size_t)u * 128 + k];
            } else if (k < 256) {
                v = agg1[((size_t)BATCH_MAX + u) * 128 + (k - 128)];
            } else {
                int n = ni[u];
                v = bf2f(x1[(size_t)n * 128 + (k - 256)]);
            }
        }
        As[r][k] = v;
    }
    __syncthreads();
    float acc[G2_ROWS];
#pragma unroll
    for (int r = 0; r < G2_ROWS; r++) acc[r] = 0.f;
    for (int k = 0; k < 384; k += 4) {
        const float w0 = Wst[(k + 0) * 64 + o];
        const float w1 = Wst[(k + 1) * 64 + o];
        const float w2 = Wst[(k + 2) * 64 + o];
        const float w3 = Wst[(k + 3) * 64 + o];
#pragma unroll
        for (int r = 0; r < G2_ROWS; r++) {
            const float4 a = *(const float4*)&As[r][k];
            acc[r] = fmaf(a.x, w0, acc[r]);
            acc[r] = fmaf(a.y, w1, acc[r]);
            acc[r] = fmaf(a.z, w2, acc[r]);
            acc[r] = fmaf(a.w, w3, acc[r]);
        }
    }
    const float b = bias[o];
    for (int r = 0; r < G2_ROWS; r++) {
        int u = row0 + r;
        if (u < B) x2[(size_t)u * 64 + o] = acc[r] + b;
    }
}

// ---------------- MLP head ----------------
__global__ __launch_bounds__(64) void mlp_kernel(const float* __restrict__ x2,
                                                 const float* __restrict__ W1, const float* __restrict__ b1,
                                                 const float* __restrict__ g1, const float* __restrict__ be1,
                                                 const float* __restrict__ W2, const float* __restrict__ b2,
                                                 const float* __restrict__ g2, const float* __restrict__ be2,
                                                 const float* __restrict__ W3, const float* __restrict__ b3,
                                                 float* __restrict__ outExpert, float* __restrict__ outProb,
                                                 int B) {
    int i = blockIdx.x;
    if (i >= B) return;
    int t = threadIdx.x;   // 0..63
    int tt = t & 31;
    float e = x2[(size_t)i * 64 + t];
    outExpert[(size_t)i * 64 + t] = e;

    float y = b1[t];
#pragma unroll
    for (int k = 0; k < 64; k++) y = fmaf(__shfl(e, k), W1[k * 64 + t], y);
    float s = y;
    for (int off = 32; off; off >>= 1) s += __shfl_xor(s, off);
    float m = s * (1.f / 64.f);
    float d = y - m;
    float vs = d * d;
    for (int off = 32; off; off >>= 1) vs += __shfl_xor(vs, off);
    float h1 = fmaxf(fmaf(g1[t] * d, rsqrtf(vs * (1.f / 64.f) + 1e-5f), be1[t]), 0.f);

    float y2 = b2[tt];
#pragma unroll
    for (int k = 0; k < 64; k++) y2 = fmaf(__shfl(h1, k), W2[k * 32 + tt], y2);
    float s2 = y2;
    for (int off = 16; off; off >>= 1) s2 += __shfl_xor(s2, off);
    float m2 = s2 * (1.f / 32.f);
    float d2 = y2 - m2;
    float v2 = d2 * d2;
    for (int off = 16; off; off >>= 1) v2 += __shfl_xor(v2, off);
    float h2 = fmaxf(fmaf(g2[tt] * d2, rsqrtf(v2 * (1.f / 32.f) + 1e-5f), be2[tt]), 0.f);

    float p = h2 * W3[tt];
    for (int off = 16; off; off >>= 1) p += __shfl_xor(p, off);
    if (t == 0) outProb[i] = 1.f / (1.f + expf(-(p + b3[0])));
}

extern "C" void kernel_launch(void* const* d_in, const int* in_sizes, int n_in,
                              void* d_out, int out_size, void* d_ws, size_t ws_size,
                              hipStream_t stream) {
    const int*   node_indices = (const int*)d_in[0];
    const int*   edge_index   = (const int*)d_in[1];
    const int*   edge_type    = (const int*)d_in[2];
    const float* x_feat       = (const float*)d_in[3];
    const float* basis0       = (const float*)d_in[4];
    const float* comp0        = (const float*)d_in[5];
    const float* root0        = (const float*)d_in[6];
    const float* bias0        = (const float*)d_in[7];
    const float* basis1       = (const float*)d_in[8];
    const float* comp1        = (const float*)d_in[9];
    const float* root1        = (const float*)d_in[10];
    const float* bias1        = (const float*)d_in[11];
    const float* W1 = (const float*)d_in[12];
    const float* b1 = (const float*)d_in[13];
    const float* g1 = (const float*)d_in[14];
    const float* be1 = (const float*)d_in[15];
    const float* W2 = (const float*)d_in[16];
    const float* b2 = (const float*)d_in[17];
    const float* g2 = (const float*)d_in[18];
    const float* be2 = (const float*)d_in[19];
    const float* W3 = (const float*)d_in[20];
    const float* b3 = (const float*)d_in[21];

    const int B = in_sizes[0];
    const int E = in_sizes[1] / 2;
    const int* src = edge_index;
    const int* dst = edge_index + E;
    const int nb = (N_NODES + 255) / 256;   // 391

    // ---- workspace carve-out (256B aligned) ----
    size_t off = 0;
    auto alloc = [&](size_t sz) { size_t o = off; off = (off + sz + 255) & ~(size_t)255; return o; };
    char* ws = (char*)d_ws;
    ushort* xb    = (ushort*)(ws + alloc((size_t)N_NODES * 128 * 2));
    ushort* Amat  = (ushort*)(ws + alloc((size_t)N_NODES * 384 * 2));
    ushort* x1b   = (ushort*)(ws + alloc((size_t)N_NODES * 128 * 2));
    int*   cnt    = (int*)  (ws + alloc((size_t)N_NODES * 2 * 4));
    int*   rowptr = (int*)  (ws + alloc((size_t)(N_NODES + 1) * 4));
    int*   cursor = (int*)  (ws + alloc((size_t)N_NODES * 4));
    int*   partial= (int*)  (ws + alloc((size_t)(nb + 1) * 4));
    int*   adj    = (int*)  (ws + alloc((size_t)E * 4));
    ushort* Wt0b  = (ushort*)(ws + alloc((size_t)128 * 384 * 2));
    float* Wst1   = (float*)(ws + alloc((size_t)384 * 64 * 4));
    float* agg1   = (float*)(ws + alloc((size_t)NREL * BATCH_MAX * 128 * 4));
    float* x2     = (float*)(ws + alloc((size_t)BATCH_MAX * 64 * 4));

    float* outExpert = (float*)d_out;
    float* outProb   = (float*)d_out + (size_t)B * 64;

    hipMemsetAsync(cnt, 0, (size_t)N_NODES * 2 * 4, stream);

    tobf16_kernel<<<(N_NODES * 128 / 4 + 255) / 256, 256, 0, stream>>>(x_feat, xb, N_NODES * 128);
    build_w0t_kernel<<<(384 * 128 + 255) / 256, 256, 0, stream>>>(basis0, comp0, root0, Wt0b);
    build_w1_kernel<<<(384 * 64 + 255) / 256, 256, 0, stream>>>(basis1, comp1, root1, Wst1);

    // ---- CSR build ----
    hist_kernel<<<(E + 255) / 256, 256, 0, stream>>>(dst, edge_type, cnt, E);
    scan1_kernel<<<nb, 256, 0, stream>>>(cnt, rowptr, partial);
    scan2_kernel<<<1, 512, 0, stream>>>(partial, nb);
    scan3_kernel<<<nb, 256, 0, stream>>>(rowptr, cursor, partial, E);
    fill_kernel<<<(E + 255) / 256, 256, 0, stream>>>(src, dst, edge_type, cursor, adj, E);

    // ---- layer 0 ----
    gather0_kernel<<<(N_NODES * 64 + 255) / 256, 256, 0, stream>>>(rowptr, adj, cnt, xb, Amat);
    gemm0_kernel<<<(N_NODES + BM - 1) / BM, 256, 0, stream>>>(Amat, Wt0b, bias0, x1b);

    // ---- layer 1 (batch rows only) ----
    gather1_kernel<<<((size_t)B * 64 + 255) / 256, 256, 0, stream>>>(node_indices, rowptr, adj, cnt, x1b, agg1, B);
    gemm2_kernel<<<(B + G2_ROWS - 1) / G2_ROWS, 64, 0, stream>>>(agg1, x1b, node_indices, Wst1, bias1, x2, B);

    // ---- head ----
    mlp_kernel<<<B, 64, 0, stream>>>(x2, W1, b1, g1, be1, W2, b2, g2, be2, W3, b3,
                                     outExpert, outProb, B);
}

// Round 6
// 288.401 us; speedup vs baseline: 6.5707x; 1.4557x over previous
//
#include <hip/hip_runtime.h>
#include <math.h>

#define N_NODES 100000
#define NREL 2
#define BATCH_MAX 4096
#define G2_ROWS 16
#define BSHIFT 8
#define NBUCK ((N_NODES + 255) >> 8)   // 391
#define EPB 4096                       // edges per block in binA/binB

typedef __attribute__((ext_vector_type(8))) short bf16x8;
typedef __attribute__((ext_vector_type(4))) float f32x4;

__device__ inline ushort f2bf(float f) {
    unsigned u = __float_as_uint(f);
    u += 0x7FFF + ((u >> 16) & 1);
    return (ushort)(u >> 16);
}
__device__ inline float bf2f(ushort h) {
    return __uint_as_float(((unsigned)h) << 16);
}

// ---------------- x_feat -> bf16 ----------------
__global__ void tobf16_kernel(const float* __restrict__ x, ushort* __restrict__ xb, int total) {
    int i = (blockIdx.x * blockDim.x + threadIdx.x) * 4;
    if (i >= total) return;
    float4 v = *(const float4*)(x + i);
    uint2 p;
    p.x = ((unsigned)f2bf(v.x)) | (((unsigned)f2bf(v.y)) << 16);
    p.y = ((unsigned)f2bf(v.z)) | (((unsigned)f2bf(v.w)) << 16);
    *(uint2*)(xb + i) = p;
}

// ---------------- weight stacking ----------------
__global__ void build_w0t_kernel(const float* __restrict__ basis, const float* __restrict__ comp,
                                 const float* __restrict__ root, ushort* __restrict__ Wt) {
    int idx = blockIdx.x * blockDim.x + threadIdx.x;
    if (idx >= 384 * 128) return;
    int k = idx >> 7, o = idx & 127;
    float v;
    if (k < 256) {
        int r = k >> 7;
        int i = k & 127;
        v = comp[r * 2 + 0] * basis[(size_t)(0 * 128 + i) * 128 + o]
          + comp[r * 2 + 1] * basis[(size_t)(1 * 128 + i) * 128 + o];
    } else {
        v = root[(size_t)(k - 256) * 128 + o];
    }
    Wt[(size_t)o * 384 + k] = f2bf(v);
}

__global__ void build_w1_kernel(const float* __restrict__ basis, const float* __restrict__ comp,
                                const float* __restrict__ root, float* __restrict__ Wst) {
    int idx = blockIdx.x * blockDim.x + threadIdx.x;
    if (idx >= 384 * 64) return;
    int k = idx / 64, o = idx % 64;
    float v;
    if (k < 256) {
        int r = k >> 7;
        int i = k & 127;
        v = comp[r * 2 + 0] * basis[(size_t)(0 * 128 + i) * 64 + o]
          + comp[r * 2 + 1] * basis[(size_t)(1 * 128 + i) * 64 + o];
    } else {
        v = root[(size_t)(k - 256) * 64 + o];
    }
    Wst[idx] = v;
}

// ---------------- CSR build: bucketed counting sort ----------------
// binA: bucket histogram via LDS
__global__ __launch_bounds__(256) void binA_kernel(const int* __restrict__ dst,
                                                   int* __restrict__ bucketCnt, int E) {
    __shared__ int h[NBUCK];
    const int tid = threadIdx.x;
    for (int b = tid; b < NBUCK; b += 256) h[b] = 0;
    __syncthreads();
    const int e0 = blockIdx.x * EPB;
#pragma unroll
    for (int i = 0; i < EPB / 256; i++) {
        int e = e0 + i * 256 + tid;
        if (e < E) atomicAdd(&h[dst[e] >> BSHIFT], 1);
    }
    __syncthreads();
    for (int b = tid; b < NBUCK; b += 256) if (h[b]) atomicAdd(&bucketCnt[b], h[b]);
}

// bscan: exclusive scan of bucket counts (NBUCK <= 512)
__global__ void bscan_kernel(const int* __restrict__ bucketCnt, int* __restrict__ bucketBase,
                             int* __restrict__ bucketCur, int* __restrict__ rowptr, int E) {
    __shared__ int s[512];
    int t = threadIdx.x;
    int v = (t < NBUCK) ? bucketCnt[t] : 0;
    s[t] = v;
    __syncthreads();
    for (int off = 1; off < 512; off <<= 1) {
        int u = (t >= off) ? s[t - off] : 0;
        __syncthreads();
        s[t] += u;
        __syncthreads();
    }
    if (t < NBUCK) {
        int excl = s[t] - v;
        bucketBase[t] = excl;
        bucketCur[t] = excl;
    }
    if (t == 0) rowptr[N_NODES] = E;
}

// binB: binned scatter into bucket regions (coalesced-ish bursts)
// tmp entry: src | (etype<<20) | (dstLocal<<21)
__global__ __launch_bounds__(256) void binB_kernel(const int* __restrict__ src,
                                                   const int* __restrict__ dst,
                                                   const int* __restrict__ etype,
                                                   int* __restrict__ bucketCur,
                                                   int* __restrict__ tmp, int E) {
    __shared__ int hCnt[NBUCK];
    __shared__ int hBase[NBUCK];
    __shared__ int hCur[NBUCK];
    const int tid = threadIdx.x;
    for (int b = tid; b < NBUCK; b += 256) { hCnt[b] = 0; hCur[b] = 0; }
    __syncthreads();
    const int e0 = blockIdx.x * EPB;
#pragma unroll
    for (int i = 0; i < EPB / 256; i++) {
        int e = e0 + i * 256 + tid;
        if (e < E) atomicAdd(&hCnt[dst[e] >> BSHIFT], 1);
    }
    __syncthreads();
    for (int b = tid; b < NBUCK; b += 256) {
        int c = hCnt[b];
        hBase[b] = c ? atomicAdd(&bucketCur[b], c) : 0;
    }
    __syncthreads();
#pragma unroll
    for (int i = 0; i < EPB / 256; i++) {
        int e = e0 + i * 256 + tid;
        if (e < E) {
            int d = dst[e];
            int b = d >> BSHIFT;
            int r = atomicAdd(&hCur[b], 1);
            tmp[hBase[b] + r] = src[e] | (etype[e] << 20) | ((d & 255) << 21);
        }
    }
}

// binC: per-bucket local counting sort by node; writes cnt, rowptr, adj
__global__ __launch_bounds__(256) void binC_kernel(const int* __restrict__ tmp,
                                                   const int* __restrict__ bucketBase,
                                                   const int* __restrict__ bucketCnt,
                                                   int* __restrict__ adj, int* __restrict__ cnt,
                                                   int* __restrict__ rowptr) {
    __shared__ int nc[512];      // per-local-node per-rel counts
    __shared__ int nbase[256];   // per-local-node exclusive offset
    __shared__ int ncur[256];
    __shared__ int sc[256];
    const int tid = threadIdx.x;
    const int b = blockIdx.x;
    const int base = bucketBase[b];
    const int m = bucketCnt[b];
    const int node0 = b << BSHIFT;
    const int nn = min(256, N_NODES - node0);

    nc[tid] = 0; nc[tid + 256] = 0; ncur[tid] = 0;
    __syncthreads();
    for (int i = tid; i < m; i += 256) {
        int v = tmp[base + i];
        atomicAdd(&nc[((v >> 21) & 255) * 2 + ((v >> 20) & 1)], 1);
    }
    __syncthreads();
    int tot = 0;
    if (tid < nn) {
        int c0 = nc[tid * 2], c1 = nc[tid * 2 + 1];
        cnt[(size_t)(node0 + tid) * 2] = c0;
        cnt[(size_t)(node0 + tid) * 2 + 1] = c1;
        tot = c0 + c1;
    }
    sc[tid] = tot;
    __syncthreads();
    for (int off = 1; off < 256; off <<= 1) {
        int u = (tid >= off) ? sc[tid - off] : 0;
        __syncthreads();
        sc[tid] += u;
        __syncthreads();
    }
    int excl = sc[tid] - tot;
    nbase[tid] = excl;
    if (tid < nn) rowptr[node0 + tid] = base + excl;
    __syncthreads();
    for (int i = tid; i < m; i += 256) {
        int v = tmp[base + i];
        int dl = (v >> 21) & 255;
        int pos = base + nbase[dl] + atomicAdd(&ncur[dl], 1);
        adj[pos] = v & 0x1FFFFF;
    }
}

// ---------------- gather0: one wave per node, builds A[N][384] bf16 ----------------
__global__ __launch_bounds__(256) void gather0_kernel(const int* __restrict__ rowptr,
                                                      const int* __restrict__ adj,
                                                      const int* __restrict__ cnt,
                                                      const ushort* __restrict__ xb,
                                                      ushort* __restrict__ A) {
    int g = blockIdx.x * blockDim.x + threadIdx.x;
    int n = g >> 6, lane = g & 63;
    if (n >= N_NODES) return;
    float a0x = 0.f, a0y = 0.f, a1x = 0.f, a1y = 0.f;
    const int beg = rowptr[n], end = rowptr[n + 1];
    int i = beg;
    for (; i + 3 < end; i += 4) {   // 4 edges in flight
        const int p0 = adj[i], p1 = adj[i + 1], p2 = adj[i + 2], p3 = adj[i + 3];
        const unsigned u0 = *(const unsigned*)(xb + (size_t)(p0 & 0xFFFFF) * 128 + lane * 2);
        const unsigned u1 = *(const unsigned*)(xb + (size_t)(p1 & 0xFFFFF) * 128 + lane * 2);
        const unsigned u2 = *(const unsigned*)(xb + (size_t)(p2 & 0xFFFFF) * 128 + lane * 2);
        const unsigned u3 = *(const unsigned*)(xb + (size_t)(p3 & 0xFFFFF) * 128 + lane * 2);
        float lx, ly;
        lx = __uint_as_float(u0 << 16); ly = __uint_as_float(u0 & 0xFFFF0000u);
        if (p0 >> 20) { a1x += lx; a1y += ly; } else { a0x += lx; a0y += ly; }
        lx = __uint_as_float(u1 << 16); ly = __uint_as_float(u1 & 0xFFFF0000u);
        if (p1 >> 20) { a1x += lx; a1y += ly; } else { a0x += lx; a0y += ly; }
        lx = __uint_as_float(u2 << 16); ly = __uint_as_float(u2 & 0xFFFF0000u);
        if (p2 >> 20) { a1x += lx; a1y += ly; } else { a0x += lx; a0y += ly; }
        lx = __uint_as_float(u3 << 16); ly = __uint_as_float(u3 & 0xFFFF0000u);
        if (p3 >> 20) { a1x += lx; a1y += ly; } else { a0x += lx; a0y += ly; }
    }
    for (; i < end; i++) {
        const int p0 = adj[i];
        const unsigned u0 = *(const unsigned*)(xb + (size_t)(p0 & 0xFFFFF) * 128 + lane * 2);
        float lx = __uint_as_float(u0 << 16), ly = __uint_as_float(u0 & 0xFFFF0000u);
        if (p0 >> 20) { a1x += lx; a1y += ly; } else { a0x += lx; a0y += ly; }
    }
    const int c0 = cnt[n * 2], c1 = cnt[n * 2 + 1];
    const float i0 = c0 > 0 ? 1.f / (float)c0 : 0.f;
    const float i1 = c1 > 0 ? 1.f / (float)c1 : 0.f;
    ushort* out = A + (size_t)n * 384 + lane * 2;
    *(unsigned*)(out)       = ((unsigned)f2bf(a0x * i0)) | (((unsigned)f2bf(a0y * i0)) << 16);
    *(unsigned*)(out + 128) = ((unsigned)f2bf(a1x * i1)) | (((unsigned)f2bf(a1y * i1)) << 16);
    *(unsigned*)(out + 256) = *(const unsigned*)(xb + (size_t)n * 128 + lane * 2);
}

// ---------------- gemm0 (MFMA bf16): x1[N][128] = relu(A[N][384] @ W + bias) ----------------
#define BM 128
#define BK 64
__global__ __launch_bounds__(256) void gemm0_kernel(const ushort* __restrict__ A,
                                                    const ushort* __restrict__ Wt,   // [128][384]
                                                    const float* __restrict__ bias,
                                                    ushort* __restrict__ x1) {
    __shared__ ushort As[BM][BK + 8];
    __shared__ ushort Ws[128][BK + 8];
    const int tid = threadIdx.x;
    const int lane = tid & 63;
    const int w = tid >> 6;
    const int row0 = blockIdx.x * BM;

    f32x4 acc[2][8];
#pragma unroll
    for (int t = 0; t < 2; t++)
#pragma unroll
        for (int c = 0; c < 8; c++) acc[t][c] = (f32x4)0.f;

    for (int kc = 0; kc < 384; kc += BK) {
        __syncthreads();
#pragma unroll
        for (int q = 0; q < 4; q++) {
            const int seg = q * 256 + tid;       // 0..1023
            const int row = seg >> 3;            // 0..127
            const int sk = (seg & 7) * 8;
            const int gr = min(row0 + row, N_NODES - 1);
            *(uint4*)&As[row][sk] = *(const uint4*)&A[(size_t)gr * 384 + kc + sk];
            *(uint4*)&Ws[row][sk] = *(const uint4*)&Wt[(size_t)row * 384 + kc + sk];
        }
        __syncthreads();
#pragma unroll
        for (int k2 = 0; k2 < 2; k2++) {
            const int kk = k2 * 32 + (lane >> 4) * 8;
            const bf16x8 af0 = *(const bf16x8*)&As[w * 32 + (lane & 15)][kk];
            const bf16x8 af1 = *(const bf16x8*)&As[w * 32 + 16 + (lane & 15)][kk];
            bf16x8 bf[8];
#pragma unroll
            for (int c = 0; c < 8; c++) bf[c] = *(const bf16x8*)&Ws[c * 16 + (lane & 15)][kk];
#pragma unroll
            for (int c = 0; c < 8; c++) {
                acc[0][c] = __builtin_amdgcn_mfma_f32_16x16x32_bf16(af0, bf[c], acc[0][c], 0, 0, 0);
                acc[1][c] = __builtin_amdgcn_mfma_f32_16x16x32_bf16(af1, bf[c], acc[1][c], 0, 0, 0);
            }
        }
    }

    // D layout: col = lane&15, row = (lane>>4)*4 + j
#pragma unroll
    for (int c = 0; c < 8; c++) {
        const int col = c * 16 + (lane & 15);
        const float b = bias[col];
#pragma unroll
        for (int t = 0; t < 2; t++) {
#pragma unroll
            for (int j = 0; j < 4; j++) {
                const int n = row0 + w * 32 + t * 16 + (lane >> 4) * 4 + j;
                if (n < N_NODES) x1[(size_t)n * 128 + col] = f2bf(fmaxf(acc[t][c][j] + b, 0.f));
            }
        }
    }
}

// ---------------- layer 1 gather (batch slots only) ----------------
__global__ void gather1_kernel(const int* __restrict__ ni, const int* __restrict__ rowptr,
                               const int* __restrict__ adj, const int* __restrict__ cnt,
                               const ushort* __restrict__ x1, float* __restrict__ agg1, int B) {
    int g = blockIdx.x * blockDim.x + threadIdx.x;
    int u = g >> 6, lane = g & 63;
    if (u >= B) return;
    int n = ni[u];
    float a0x = 0.f, a0y = 0.f, a1x = 0.f, a1y = 0.f;
    const int beg = rowptr[n], end = rowptr[n + 1];
    int i = beg;
    for (; i + 1 < end; i += 2) {
        const int p0 = adj[i], p1 = adj[i + 1];
        const unsigned u0 = *(const unsigned*)(x1 + (size_t)(p0 & 0xFFFFF) * 128 + lane * 2);
        const unsigned u1 = *(const unsigned*)(x1 + (size_t)(p1 & 0xFFFFF) * 128 + lane * 2);
        float lx, ly;
        lx = __uint_as_float(u0 << 16); ly = __uint_as_float(u0 & 0xFFFF0000u);
        if (p0 >> 20) { a1x += lx; a1y += ly; } else { a0x += lx; a0y += ly; }
        lx = __uint_as_float(u1 << 16); ly = __uint_as_float(u1 & 0xFFFF0000u);
        if (p1 >> 20) { a1x += lx; a1y += ly; } else { a0x += lx; a0y += ly; }
    }
    if (i < end) {
        const int p0 = adj[i];
        const unsigned u0 = *(const unsigned*)(x1 + (size_t)(p0 & 0xFFFFF) * 128 + lane * 2);
        float lx = __uint_as_float(u0 << 16), ly = __uint_as_float(u0 & 0xFFFF0000u);
        if (p0 >> 20) { a1x += lx; a1y += ly; } else { a0x += lx; a0y += ly; }
    }
    const int c0 = cnt[n * 2], c1 = cnt[n * 2 + 1];
    const float i0 = c0 > 0 ? 1.f / (float)c0 : 0.f;
    const float i1 = c1 > 0 ? 1.f / (float)c1 : 0.f;
    *(float2*)(agg1 + (size_t)u * 128 + lane * 2) = make_float2(a0x * i0, a0y * i0);
    *(float2*)(agg1 + ((size_t)BATCH_MAX + u) * 128 + lane * 2) = make_float2(a1x * i1, a1y * i1);
}

// ---------------- gemm2: x2[B][64] = A @ Wst1 + bias1 ----------------
__global__ __launch_bounds__(64) void gemm2_kernel(const float* __restrict__ agg1,
                                                   const ushort* __restrict__ x1,
                                                   const int* __restrict__ ni,
                                                   const float* __restrict__ Wst,
                                                   const float* __restrict__ bias,
                                                   float* __restrict__ x2, int B) {
    __shared__ float As[G2_ROWS][384];
    const int o = threadIdx.x;  // 0..63
    const int row0 = blockIdx.x * G2_ROWS;
    for (int idx = threadIdx.x; idx < G2_ROWS * 384; idx += 64) {
        int r = idx / 384, k = idx - r * 384;
        int u = row0 + r;
        float v = 0.f;
        if (u < B) {
            if (k < 128) {
                v = agg1[(size_t)u * 128 + k];
            } else if (k < 256) {
                v = agg1[((size_t)BATCH_MAX + u) * 128 + (k - 128)];
            } else {
                int n = ni[u];
                v = bf2f(x1[(size_t)n * 128 + (k - 256)]);
            }
        }
        As[r][k] = v;
    }
    __syncthreads();
    float acc[G2_ROWS];
#pragma unroll
    for (int r = 0; r < G2_ROWS; r++) acc[r] = 0.f;
    for (int k = 0; k < 384; k += 4) {
        const float w0 = Wst[(k + 0) * 64 + o];
        const float w1 = Wst[(k + 1) * 64 + o];
        const float w2 = Wst[(k + 2) * 64 + o];
        const float w3 = Wst[(k + 3) * 64 + o];
#pragma unroll
        for (int r = 0; r < G2_ROWS; r++) {
            const float4 a = *(const float4*)&As[r][k];
            acc[r] = fmaf(a.x, w0, acc[r]);
            acc[r] = fmaf(a.y, w1, acc[r]);
            acc[r] = fmaf(a.z, w2, acc[r]);
            acc[r] = fmaf(a.w, w3, acc[r]);
        }
    }
    const float b = bias[o];
    for (int r = 0; r < G2_ROWS; r++) {
        int u = row0 + r;
        if (u < B) x2[(size_t)u * 64 + o] = acc[r] + b;
    }
}

// ---------------- MLP head ----------------
__global__ __launch_bounds__(64) void mlp_kernel(const float* __restrict__ x2,
                                                 const float* __restrict__ W1, const float* __restrict__ b1,
                                                 const float* __restrict__ g1, const float* __restrict__ be1,
                                                 const float* __restrict__ W2, const float* __restrict__ b2,
                                                 const float* __restrict__ g2, const float* __restrict__ be2,
                                                 const float* __restrict__ W3, const float* __restrict__ b3,
                                                 float* __restrict__ outExpert, float* __restrict__ outProb,
                                                 int B) {
    int i = blockIdx.x;
    if (i >= B) return;
    int t = threadIdx.x;   // 0..63
    int tt = t & 31;
    float e = x2[(size_t)i * 64 + t];
    outExpert[(size_t)i * 64 + t] = e;

    float y = b1[t];
#pragma unroll
    for (int k = 0; k < 64; k++) y = fmaf(__shfl(e, k), W1[k * 64 + t], y);
    float s = y;
    for (int off = 32; off; off >>= 1) s += __shfl_xor(s, off);
    float m = s * (1.f / 64.f);
    float d = y - m;
    float vs = d * d;
    for (int off = 32; off; off >>= 1) vs += __shfl_xor(vs, off);
    float h1 = fmaxf(fmaf(g1[t] * d, rsqrtf(vs * (1.f / 64.f) + 1e-5f), be1[t]), 0.f);

    float y2 = b2[tt];
#pragma unroll
    for (int k = 0; k < 64; k++) y2 = fmaf(__shfl(h1, k), W2[k * 32 + tt], y2);
    float s2 = y2;
    for (int off = 16; off; off >>= 1) s2 += __shfl_xor(s2, off);
    float m2 = s2 * (1.f / 32.f);
    float d2 = y2 - m2;
    float v2 = d2 * d2;
    for (int off = 16; off; off >>= 1) v2 += __shfl_xor(v2, off);
    float h2 = fmaxf(fmaf(g2[tt] * d2, rsqrtf(v2 * (1.f / 32.f) + 1e-5f), be2[tt]), 0.f);

    float p = h2 * W3[tt];
    for (int off = 16; off; off >>= 1) p += __shfl_xor(p, off);
    if (t == 0) outProb[i] = 1.f / (1.f + expf(-(p + b3[0])));
}

extern "C" void kernel_launch(void* const* d_in, const int* in_sizes, int n_in,
                              void* d_out, int out_size, void* d_ws, size_t ws_size,
                              hipStream_t stream) {
    const int*   node_indices = (const int*)d_in[0];
    const int*   edge_index   = (const int*)d_in[1];
    const int*   edge_type    = (const int*)d_in[2];
    const float* x_feat       = (const float*)d_in[3];
    const float* basis0       = (const float*)d_in[4];
    const float* comp0        = (const float*)d_in[5];
    const float* root0        = (const float*)d_in[6];
    const float* bias0        = (const float*)d_in[7];
    const float* basis1       = (const float*)d_in[8];
    const float* comp1        = (const float*)d_in[9];
    const float* root1        = (const float*)d_in[10];
    const float* bias1        = (const float*)d_in[11];
    const float* W1 = (const float*)d_in[12];
    const float* b1 = (const float*)d_in[13];
    const float* g1 = (const float*)d_in[14];
    const float* be1 = (const float*)d_in[15];
    const float* W2 = (const float*)d_in[16];
    const float* b2 = (const float*)d_in[17];
    const float* g2 = (const float*)d_in[18];
    const float* be2 = (const float*)d_in[19];
    const float* W3 = (const float*)d_in[20];
    const float* b3 = (const float*)d_in[21];

    const int B = in_sizes[0];
    const int E = in_sizes[1] / 2;
    const int* src = edge_index;
    const int* dst = edge_index + E;
    const int nblk = (E + EPB - 1) / EPB;

    // ---- workspace carve-out (256B aligned) ----
    size_t off = 0;
    auto alloc = [&](size_t sz) { size_t o = off; off = (off + sz + 255) & ~(size_t)255; return o; };
    char* ws = (char*)d_ws;
    ushort* xb    = (ushort*)(ws + alloc((size_t)N_NODES * 128 * 2));
    ushort* Amat  = (ushort*)(ws + alloc((size_t)N_NODES * 384 * 2));
    ushort* x1b   = (ushort*)(ws + alloc((size_t)N_NODES * 128 * 2));
    int*   cnt    = (int*)  (ws + alloc((size_t)N_NODES * 2 * 4));
    int*   rowptr = (int*)  (ws + alloc((size_t)(N_NODES + 1) * 4));
    int*   adj    = (int*)  (ws + alloc((size_t)E * 4));
    int*   tmp    = (int*)  (ws + alloc((size_t)E * 4));
    int*   bucketCnt  = (int*)(ws + alloc((size_t)NBUCK * 4));
    int*   bucketBase = (int*)(ws + alloc((size_t)NBUCK * 4));
    int*   bucketCur  = (int*)(ws + alloc((size_t)NBUCK * 4));
    ushort* Wt0b  = (ushort*)(ws + alloc((size_t)128 * 384 * 2));
    float* Wst1   = (float*)(ws + alloc((size_t)384 * 64 * 4));
    float* agg1   = (float*)(ws + alloc((size_t)NREL * BATCH_MAX * 128 * 4));
    float* x2     = (float*)(ws + alloc((size_t)BATCH_MAX * 64 * 4));

    float* outExpert = (float*)d_out;
    float* outProb   = (float*)d_out + (size_t)B * 64;

    hipMemsetAsync(bucketCnt, 0, (size_t)NBUCK * 4, stream);

    tobf16_kernel<<<(N_NODES * 128 / 4 + 255) / 256, 256, 0, stream>>>(x_feat, xb, N_NODES * 128);
    build_w0t_kernel<<<(384 * 128 + 255) / 256, 256, 0, stream>>>(basis0, comp0, root0, Wt0b);
    build_w1_kernel<<<(384 * 64 + 255) / 256, 256, 0, stream>>>(basis1, comp1, root1, Wst1);

    // ---- CSR build (bucketed counting sort) ----
    binA_kernel<<<nblk, 256, 0, stream>>>(dst, bucketCnt, E);
    bscan_kernel<<<1, 512, 0, stream>>>(bucketCnt, bucketBase, bucketCur, rowptr, E);
    binB_kernel<<<nblk, 256, 0, stream>>>(src, dst, edge_type, bucketCur, tmp, E);
    binC_kernel<<<NBUCK, 256, 0, stream>>>(tmp, bucketBase, bucketCnt, adj, cnt, rowptr);

    // ---- layer 0 ----
    gather0_kernel<<<(N_NODES * 64 + 255) / 256, 256, 0, stream>>>(rowptr, adj, cnt, xb, Amat);
    gemm0_kernel<<<(N_NODES + BM - 1) / BM, 256, 0, stream>>>(Amat, Wt0b, bias0, x1b);

    // ---- layer 1 (batch rows only) ----
    gather1_kernel<<<((size_t)B * 64 + 255) / 256, 256, 0, stream>>>(node_indices, rowptr, adj, cnt, x1b, agg1, B);
    gemm2_kernel<<<(B + G2_ROWS - 1) / G2_ROWS, 64, 0, stream>>>(agg1, x1b, node_indices, Wst1, bias1, x2, B);

    // ---- head ----
    mlp_kernel<<<B, 64, 0, stream>>>(x2, W1, b1, g1, be1, W2, b2, g2, be2, W3, b3,
                                     outExpert, outProb, B);
}

// Round 8
// 242.787 us; speedup vs baseline: 7.8052x; 1.1879x over previous
//
#include <hip/hip_runtime.h>
#include <math.h>

#define N_NODES 100000
#define NREL 2
#define BATCH_MAX 4096
#define BSHIFT 8
#define NBUCK ((N_NODES + 255) >> 8)   // 391
#define EPB 4096                       // edges per block in binA/binB
#define NBX 12500                      // tobf16 blocks: N*128/4/256

typedef __attribute__((ext_vector_type(8))) short bf16x8;
typedef __attribute__((ext_vector_type(4))) float f32x4;

__device__ inline ushort f2bf(float f) {
    unsigned u = __float_as_uint(f);
    u += 0x7FFF + ((u >> 16) & 1);
    return (ushort)(u >> 16);
}
__device__ inline float bf2f(ushort h) {
    return __uint_as_float(((unsigned)h) << 16);
}

// ---------------- fused prep: x->bf16 | W0 stack (bf16,T) | W1 stack (f32) ----------------
__global__ __launch_bounds__(256) void prep_kernel(const float* __restrict__ x, ushort* __restrict__ xb,
                                                   const float* __restrict__ basis0, const float* __restrict__ comp0,
                                                   const float* __restrict__ root0, ushort* __restrict__ Wt0,
                                                   const float* __restrict__ basis1, const float* __restrict__ comp1,
                                                   const float* __restrict__ root1, float* __restrict__ Wst1) {
    const int bid = blockIdx.x;
    const int tid = threadIdx.x;
    if (bid < NBX) {
        int i = (bid * 256 + tid) * 4;
        float4 v = *(const float4*)(x + i);
        uint2 p;
        p.x = ((unsigned)f2bf(v.x)) | (((unsigned)f2bf(v.y)) << 16);
        p.y = ((unsigned)f2bf(v.z)) | (((unsigned)f2bf(v.w)) << 16);
        *(uint2*)(xb + i) = p;
    } else if (bid < NBX + 192) {
        int idx = (bid - NBX) * 256 + tid;   // < 384*128
        int k = idx >> 7, o = idx & 127;
        float v;
        if (k < 256) {
            int r = k >> 7, i = k & 127;
            v = comp0[r * 2 + 0] * basis0[(size_t)(0 * 128 + i) * 128 + o]
              + comp0[r * 2 + 1] * basis0[(size_t)(1 * 128 + i) * 128 + o];
        } else {
            v = root0[(size_t)(k - 256) * 128 + o];
        }
        Wt0[(size_t)o * 384 + k] = f2bf(v);
    } else {
        int idx = (bid - NBX - 192) * 256 + tid;  // < 384*64
        int k = idx / 64, o = idx & 63;
        float v;
        if (k < 256) {
            int r = k >> 7, i = k & 127;
            v = comp1[r * 2 + 0] * basis1[(size_t)(0 * 128 + i) * 64 + o]
              + comp1[r * 2 + 1] * basis1[(size_t)(1 * 128 + i) * 64 + o];
        } else {
            v = root1[(size_t)(k - 256) * 64 + o];
        }
        Wst1[idx] = v;
    }
}

// ---------------- CSR build: bucketed counting sort ----------------
__global__ __launch_bounds__(256) void binA_kernel(const int* __restrict__ dst,
                                                   int* __restrict__ bucketCnt,
                                                   int* __restrict__ blockHist, int E) {
    __shared__ int h[NBUCK];
    const int tid = threadIdx.x;
    for (int b = tid; b < NBUCK; b += 256) h[b] = 0;
    __syncthreads();
    const int e0 = blockIdx.x * EPB;
#pragma unroll
    for (int i = 0; i < EPB / 256; i++) {
        int e = e0 + i * 256 + tid;
        if (e < E) atomicAdd(&h[dst[e] >> BSHIFT], 1);
    }
    __syncthreads();
    const int row = blockIdx.x * NBUCK;
    for (int b = tid; b < NBUCK; b += 256) {
        int c = h[b];
        blockHist[row + b] = c;
        if (c) atomicAdd(&bucketCnt[b], c);
    }
}

__global__ void bscan_kernel(const int* __restrict__ bucketCnt, int* __restrict__ bucketBase,
                             int* __restrict__ bucketCur, int* __restrict__ rowptr, int E) {
    __shared__ int s[512];
    int t = threadIdx.x;
    int v = (t < NBUCK) ? bucketCnt[t] : 0;
    s[t] = v;
    __syncthreads();
    for (int off = 1; off < 512; off <<= 1) {
        int u = (t >= off) ? s[t - off] : 0;
        __syncthreads();
        s[t] += u;
        __syncthreads();
    }
    if (t < NBUCK) {
        int excl = s[t] - v;
        bucketBase[t] = excl;
        bucketCur[t] = excl;
    }
    if (t == 0) rowptr[N_NODES] = E;
}

// binB: binned scatter; per-block counts come from blockHist (binA) — no re-histogram
__global__ __launch_bounds__(256) void binB_kernel(const int* __restrict__ src,
                                                   const int* __restrict__ dst,
                                                   const int* __restrict__ etype,
                                                   const int* __restrict__ blockHist,
                                                   int* __restrict__ bucketCur,
                                                   int* __restrict__ tmp, int E) {
    __shared__ int hBase[NBUCK];
    __shared__ int hCur[NBUCK];
    const int tid = threadIdx.x;
    const int row = blockIdx.x * NBUCK;
    for (int b = tid; b < NBUCK; b += 256) {
        int c = blockHist[row + b];
        hBase[b] = c ? atomicAdd(&bucketCur[b], c) : 0;
        hCur[b] = 0;
    }
    __syncthreads();
    const int e0 = blockIdx.x * EPB;
#pragma unroll
    for (int i = 0; i < EPB / 256; i++) {
        int e = e0 + i * 256 + tid;
        if (e < E) {
            int d = dst[e];
            int b = d >> BSHIFT;
            int r = atomicAdd(&hCur[b], 1);
            tmp[hBase[b] + r] = src[e] | (etype[e] << 20) | ((d & 255) << 21);
        }
    }
}

// binC: per-bucket local counting sort by node; writes cnt, rowptr, adj
__global__ __launch_bounds__(256) void binC_kernel(const int* __restrict__ tmp,
                                                   const int* __restrict__ bucketBase,
                                                   const int* __restrict__ bucketCnt,
                                                   int* __restrict__ adj, int* __restrict__ cnt,
                                                   int* __restrict__ rowptr) {
    __shared__ int nc[512];
    __shared__ int nbase[256];
    __shared__ int ncur[256];
    __shared__ int sc[256];
    const int tid = threadIdx.x;
    const int b = blockIdx.x;
    const int base = bucketBase[b];
    const int m = bucketCnt[b];
    const int node0 = b << BSHIFT;
    const int nn = min(256, N_NODES - node0);

    nc[tid] = 0; nc[tid + 256] = 0; ncur[tid] = 0;
    __syncthreads();
    for (int i = tid; i < m; i += 256) {
        int v = tmp[base + i];
        atomicAdd(&nc[((v >> 21) & 255) * 2 + ((v >> 20) & 1)], 1);
    }
    __syncthreads();
    int tot = 0;
    if (tid < nn) {
        int c0 = nc[tid * 2], c1 = nc[tid * 2 + 1];
        cnt[(size_t)(node0 + tid) * 2] = c0;
        cnt[(size_t)(node0 + tid) * 2 + 1] = c1;
        tot = c0 + c1;
    }
    sc[tid] = tot;
    __syncthreads();
    for (int off = 1; off < 256; off <<= 1) {
        int u = (tid >= off) ? sc[tid - off] : 0;
        __syncthreads();
        sc[tid] += u;
        __syncthreads();
    }
    int excl = sc[tid] - tot;
    nbase[tid] = excl;
    if (tid < nn) rowptr[node0 + tid] = base + excl;
    __syncthreads();
    for (int i = tid; i < m; i += 256) {
        int v = tmp[base + i];
        int dl = (v >> 21) & 255;
        int pos = base + nbase[dl] + atomicAdd(&ncur[dl], 1);
        adj[pos] = v & 0x1FFFFF;
    }
}

// ---------------- gather0: one wave per node, builds A[N][256] bf16 (agg only) ----------------
__global__ __launch_bounds__(256) void gather0_kernel(const int* __restrict__ rowptr,
                                                      const int* __restrict__ adj,
                                                      const int* __restrict__ cnt,
                                                      const ushort* __restrict__ xb,
                                                      ushort* __restrict__ A) {
    int g = blockIdx.x * blockDim.x + threadIdx.x;
    int n = g >> 6, lane = g & 63;
    if (n >= N_NODES) return;
    float a0x = 0.f, a0y = 0.f, a1x = 0.f, a1y = 0.f;
    const int beg = rowptr[n], end = rowptr[n + 1];
    int i = beg;
    for (; i + 7 < end; i += 8) {   // 8 edges in flight
        int p[8]; unsigned u[8];
#pragma unroll
        for (int j = 0; j < 8; j++) p[j] = adj[i + j];
#pragma unroll
        for (int j = 0; j < 8; j++)
            u[j] = *(const unsigned*)(xb + (size_t)(p[j] & 0xFFFFF) * 128 + lane * 2);
#pragma unroll
        for (int j = 0; j < 8; j++) {
            float lx = __uint_as_float(u[j] << 16), ly = __uint_as_float(u[j] & 0xFFFF0000u);
            if (p[j] >> 20) { a1x += lx; a1y += ly; } else { a0x += lx; a0y += ly; }
        }
    }
    for (; i < end; i++) {
        const int p0 = adj[i];
        const unsigned u0 = *(const unsigned*)(xb + (size_t)(p0 & 0xFFFFF) * 128 + lane * 2);
        float lx = __uint_as_float(u0 << 16), ly = __uint_as_float(u0 & 0xFFFF0000u);
        if (p0 >> 20) { a1x += lx; a1y += ly; } else { a0x += lx; a0y += ly; }
    }
    const int c0 = cnt[n * 2], c1 = cnt[n * 2 + 1];
    const float i0 = c0 > 0 ? 1.f / (float)c0 : 0.f;
    const float i1 = c1 > 0 ? 1.f / (float)c1 : 0.f;
    ushort* out = A + (size_t)n * 256 + lane * 2;
    *(unsigned*)(out)       = ((unsigned)f2bf(a0x * i0)) | (((unsigned)f2bf(a0y * i0)) << 16);
    *(unsigned*)(out + 128) = ((unsigned)f2bf(a1x * i1)) | (((unsigned)f2bf(a1y * i1)) << 16);
}

// ---------------- gemm0 (MFMA bf16): x1 = relu([A | x] @ W + bias) ----------------
#define BM 128
#define BK 64
__global__ __launch_bounds__(256) void gemm0_kernel(const ushort* __restrict__ A,    // [N][256]
                                                    const ushort* __restrict__ xb,   // [N][128]
                                                    const ushort* __restrict__ Wt,   // [128][384]
                                                    const float* __restrict__ bias,
                                                    ushort* __restrict__ x1) {
    __shared__ ushort As[BM][BK + 8];
    __shared__ ushort Ws[128][BK + 8];
    const int tid = threadIdx.x;
    const int lane = tid & 63;
    const int w = tid >> 6;
    const int row0 = blockIdx.x * BM;

    f32x4 acc[2][8];
#pragma unroll
    for (int t = 0; t < 2; t++)
#pragma unroll
        for (int c = 0; c < 8; c++) acc[t][c] = (f32x4)0.f;

    for (int kc = 0; kc < 384; kc += BK) {
        __syncthreads();
#pragma unroll
        for (int q = 0; q < 4; q++) {
            const int seg = q * 256 + tid;       // 0..1023
            const int row = seg >> 3;            // 0..127
            const int sk = (seg & 7) * 8;
            const int gr = min(row0 + row, N_NODES - 1);
            uint4 val;
            if (kc < 256) val = *(const uint4*)&A[(size_t)gr * 256 + kc + sk];
            else          val = *(const uint4*)&xb[(size_t)gr * 128 + (kc - 256) + sk];
            *(uint4*)&As[row][sk] = val;
            *(uint4*)&Ws[row][sk] = *(const uint4*)&Wt[(size_t)row * 384 + kc + sk];
        }
        __syncthreads();
#pragma unroll
        for (int k2 = 0; k2 < 2; k2++) {
            const int kk = k2 * 32 + (lane >> 4) * 8;
            const bf16x8 af0 = *(const bf16x8*)&As[w * 32 + (lane & 15)][kk];
            const bf16x8 af1 = *(const bf16x8*)&As[w * 32 + 16 + (lane & 15)][kk];
            bf16x8 bf[8];
#pragma unroll
            for (int c = 0; c < 8; c++) bf[c] = *(const bf16x8*)&Ws[c * 16 + (lane & 15)][kk];
#pragma unroll
            for (int c = 0; c < 8; c++) {
                acc[0][c] = __builtin_amdgcn_mfma_f32_16x16x32_bf16(af0, bf[c], acc[0][c], 0, 0, 0);
                acc[1][c] = __builtin_amdgcn_mfma_f32_16x16x32_bf16(af1, bf[c], acc[1][c], 0, 0, 0);
            }
        }
    }

    // D layout: col = lane&15, row = (lane>>4)*4 + j
#pragma unroll
    for (int c = 0; c < 8; c++) {
        const int col = c * 16 + (lane & 15);
        const float b = bias[col];
#pragma unroll
        for (int t = 0; t < 2; t++) {
#pragma unroll
            for (int j = 0; j < 4; j++) {
                const int n = row0 + w * 32 + t * 16 + (lane >> 4) * 4 + j;
                if (n < N_NODES) x1[(size_t)n * 128 + col] = f2bf(fmaxf(acc[t][c][j] + b, 0.f));
            }
        }
    }
}

// ---------------- fused tail: gather1 + gemm2 + MLP head ----------------
// 256 threads, 16 batch rows per block
__global__ __launch_bounds__(256) void tail_kernel(const int* __restrict__ ni,
                                                   const int* __restrict__ rowptr,
                                                   const int* __restrict__ adj,
                                                   const int* __restrict__ cnt,
                                                   const ushort* __restrict__ x1,
                                                   const float* __restrict__ Wst,   // [384][64]
                                                   const float* __restrict__ bias,
                                                   const float* __restrict__ W1, const float* __restrict__ b1,
                                                   const float* __restrict__ g1, const float* __restrict__ be1,
                                                   const float* __restrict__ W2, const float* __restrict__ b2,
                                                   const float* __restrict__ g2, const float* __restrict__ be2,
                                                   const float* __restrict__ W3, const float* __restrict__ b3,
                                                   float* __restrict__ outExpert, float* __restrict__ outProb,
                                                   int B) {
    __shared__ float As[16][384];
    __shared__ float x2s[16][64];
    const int tid = threadIdx.x;
    const int lane = tid & 63;
    const int w = tid >> 6;
    const int row0 = blockIdx.x * 16;

    // ---- phase 1: gather A rows [agg0 | agg1 | x1[n]] into LDS ----
    for (int j = 0; j < 4; j++) {
        const int r = w + j * 4;
        const int u = row0 + r;
        float a0x = 0.f, a0y = 0.f, a1x = 0.f, a1y = 0.f, xx = 0.f, xy = 0.f;
        if (u < B) {
            const int n = ni[u];
            const int beg = rowptr[n], end = rowptr[n + 1];
            int i = beg;
            for (; i + 1 < end; i += 2) {
                const int p0 = adj[i], p1 = adj[i + 1];
                const unsigned u0 = *(const unsigned*)(x1 + (size_t)(p0 & 0xFFFFF) * 128 + lane * 2);
                const unsigned u1 = *(const unsigned*)(x1 + (size_t)(p1 & 0xFFFFF) * 128 + lane * 2);
                float lx, ly;
                lx = __uint_as_float(u0 << 16); ly = __uint_as_float(u0 & 0xFFFF0000u);
                if (p0 >> 20) { a1x += lx; a1y += ly; } else { a0x += lx; a0y += ly; }
                lx = __uint_as_float(u1 << 16); ly = __uint_as_float(u1 & 0xFFFF0000u);
                if (p1 >> 20) { a1x += lx; a1y += ly; } else { a0x += lx; a0y += ly; }
            }
            if (i < end) {
                const int p0 = adj[i];
                const unsigned u0 = *(const unsigned*)(x1 + (size_t)(p0 & 0xFFFFF) * 128 + lane * 2);
                float lx = __uint_as_float(u0 << 16), ly = __uint_as_float(u0 & 0xFFFF0000u);
                if (p0 >> 20) { a1x += lx; a1y += ly; } else { a0x += lx; a0y += ly; }
            }
            const int c0 = cnt[n * 2], c1 = cnt[n * 2 + 1];
            const float i0 = c0 > 0 ? 1.f / (float)c0 : 0.f;
            const float i1 = c1 > 0 ? 1.f / (float)c1 : 0.f;
            a0x *= i0; a0y *= i0; a1x *= i1; a1y *= i1;
            const unsigned ux = *(const unsigned*)(x1 + (size_t)n * 128 + lane * 2);
            xx = __uint_as_float(ux << 16); xy = __uint_as_float(ux & 0xFFFF0000u);
        }
        As[r][lane * 2] = a0x;       As[r][lane * 2 + 1] = a0y;
        As[r][128 + lane * 2] = a1x; As[r][128 + lane * 2 + 1] = a1y;
        As[r][256 + lane * 2] = xx;  As[r][256 + lane * 2 + 1] = xy;
    }
    __syncthreads();

    // ---- phase 2: gemm 16x384 @ 384x64 ----
    {
        const int o = tid & 63;
        const int q = tid >> 6;
        float acc[4] = {0.f, 0.f, 0.f, 0.f};
        for (int k = 0; k < 384; k += 4) {
            const float w0 = Wst[(k + 0) * 64 + o];
            const float w1_ = Wst[(k + 1) * 64 + o];
            const float w2_ = Wst[(k + 2) * 64 + o];
            const float w3_ = Wst[(k + 3) * 64 + o];
#pragma unroll
            for (int rr = 0; rr < 4; rr++) {
                const float4 a = *(const float4*)&As[q * 4 + rr][k];
                acc[rr] = fmaf(a.x, w0, acc[rr]);
                acc[rr] = fmaf(a.y, w1_, acc[rr]);
                acc[rr] = fmaf(a.z, w2_, acc[rr]);
                acc[rr] = fmaf(a.w, w3_, acc[rr]);
            }
        }
        const float bb = bias[o];
#pragma unroll
        for (int rr = 0; rr < 4; rr++) x2s[q * 4 + rr][o] = acc[rr] + bb;
    }
    __syncthreads();

    // ---- phase 3: MLP head, wave w handles rows w*4..w*4+3 ----
    for (int rr = 0; rr < 4; rr++) {
        const int r = w * 4 + rr;
        const int i = row0 + r;
        if (i >= B) continue;
        const int t = lane;
        const int tt = lane & 31;
        float e = x2s[r][t];
        outExpert[(size_t)i * 64 + t] = e;

        float y = b1[t];
#pragma unroll
        for (int k = 0; k < 64; k++) y = fmaf(__shfl(e, k), W1[k * 64 + t], y);
        float s = y;
        for (int off = 32; off; off >>= 1) s += __shfl_xor(s, off);
        float m = s * (1.f / 64.f);
        float d = y - m;
        float vs = d * d;
        for (int off = 32; off; off >>= 1) vs += __shfl_xor(vs, off);
        float h1 = fmaxf(fmaf(g1[t] * d, rsqrtf(vs * (1.f / 64.f) + 1e-5f), be1[t]), 0.f);

        float y2 = b2[tt];
#pragma unroll
        for (int k = 0; k < 64; k++) y2 = fmaf(__shfl(h1, k), W2[k * 32 + tt], y2);
        float s2 = y2;
        for (int off = 16; off; off >>= 1) s2 += __shfl_xor(s2, off);
        float m2 = s2 * (1.f / 32.f);
        float d2 = y2 - m2;
        float v2 = d2 * d2;
        for (int off = 16; off; off >>= 1) v2 += __shfl_xor(v2, off);
        float h2 = fmaxf(fmaf(g2[tt] * d2, rsqrtf(v2 * (1.f / 32.f) + 1e-5f), be2[tt]), 0.f);

        float p = h2 * W3[tt];
        for (int off = 16; off; off >>= 1) p += __shfl_xor(p, off);
        if (t == 0) outProb[i] = 1.f / (1.f + expf(-(p + b3[0])));
    }
}

extern "C" void kernel_launch(void* const* d_in, const int* in_sizes, int n_in,
                              void* d_out, int out_size, void* d_ws, size_t ws_size,
                              hipStream_t stream) {
    const int*   node_indices = (const int*)d_in[0];
    const int*   edge_index   = (const int*)d_in[1];
    const int*   edge_type    = (const int*)d_in[2];
    const float* x_feat       = (const float*)d_in[3];
    const float* basis0       = (const float*)d_in[4];
    const float* comp0        = (const float*)d_in[5];
    const float* root0        = (const float*)d_in[6];
    const float* bias0        = (const float*)d_in[7];
    const float* basis1       = (const float*)d_in[8];
    const float* comp1        = (const float*)d_in[9];
    const float* root1        = (const float*)d_in[10];
    const float* bias1        = (const float*)d_in[11];
    const float* W1 = (const float*)d_in[12];
    const float* b1 = (const float*)d_in[13];
    const float* g1 = (const float*)d_in[14];
    const float* be1 = (const float*)d_in[15];
    const float* W2 = (const float*)d_in[16];
    const float* b2 = (const float*)d_in[17];
    const float* g2 = (const float*)d_in[18];
    const float* be2 = (const float*)d_in[19];
    const float* W3 = (const float*)d_in[20];
    const float* b3 = (const float*)d_in[21];

    const int B = in_sizes[0];
    const int E = in_sizes[1] / 2;
    const int* src = edge_index;
    const int* dst = edge_index + E;
    const int nblk = (E + EPB - 1) / EPB;

    // ---- workspace carve-out (256B aligned) ----
    size_t off = 0;
    auto alloc = [&](size_t sz) { size_t o = off; off = (off + sz + 255) & ~(size_t)255; return o; };
    char* ws = (char*)d_ws;
    ushort* xb    = (ushort*)(ws + alloc((size_t)N_NODES * 128 * 2));
    ushort* Amat  = (ushort*)(ws + alloc((size_t)N_NODES * 256 * 2));
    ushort* x1b   = (ushort*)(ws + alloc((size_t)N_NODES * 128 * 2));
    int*   cnt    = (int*)  (ws + alloc((size_t)N_NODES * 2 * 4));
    int*   rowptr = (int*)  (ws + alloc((size_t)(N_NODES + 1) * 4));
    int*   adj    = (int*)  (ws + alloc((size_t)E * 4));
    int*   tmp    = (int*)  (ws + alloc((size_t)E * 4));
    int*   blockHist  = (int*)(ws + alloc((size_t)nblk * NBUCK * 4));
    int*   bucketCnt  = (int*)(ws + alloc((size_t)NBUCK * 4));
    int*   bucketBase = (int*)(ws + alloc((size_t)NBUCK * 4));
    int*   bucketCur  = (int*)(ws + alloc((size_t)NBUCK * 4));
    ushort* Wt0b  = (ushort*)(ws + alloc((size_t)128 * 384 * 2));
    float* Wst1   = (float*)(ws + alloc((size_t)384 * 64 * 4));

    float* outExpert = (float*)d_out;
    float* outProb   = (float*)d_out + (size_t)B * 64;

    hipMemsetAsync(bucketCnt, 0, (size_t)NBUCK * 4, stream);

    prep_kernel<<<NBX + 192 + 96, 256, 0, stream>>>(x_feat, xb, basis0, comp0, root0, Wt0b,
                                                    basis1, comp1, root1, Wst1);

    // ---- CSR build (bucketed counting sort) ----
    binA_kernel<<<nblk, 256, 0, stream>>>(dst, bucketCnt, blockHist, E);
    bscan_kernel<<<1, 512, 0, stream>>>(bucketCnt, bucketBase, bucketCur, rowptr, E);
    binB_kernel<<<nblk, 256, 0, stream>>>(src, dst, edge_type, blockHist, bucketCur, tmp, E);
    binC_kernel<<<NBUCK, 256, 0, stream>>>(tmp, bucketBase, bucketCnt, adj, cnt, rowptr);

    // ---- layer 0 ----
    gather0_kernel<<<(N_NODES * 64 + 255) / 256, 256, 0, stream>>>(rowptr, adj, cnt, xb, Amat);
    gemm0_kernel<<<(N_NODES + BM - 1) / BM, 256, 0, stream>>>(Amat, xb, Wt0b, bias0, x1b);

    // ---- layer 1 + head (fused) ----
    tail_kernel<<<(B + 15) / 16, 256, 0, stream>>>(node_indices, rowptr, adj, cnt, x1b,
                                                   Wst1, bias1,
                                                   W1, b1, g1, be1, W2, b2, g2, be2, W3, b3,
                                                   outExpert, outProb, B);
}

// Round 9
// 208.809 us; speedup vs baseline: 9.0752x; 1.1627x over previous
//
#include <hip/hip_runtime.h>
#include <math.h>

#define N_NODES 100000
#define NREL 2
#define BATCH_MAX 4096
#define BSHIFT 8
#define NBUCK ((N_NODES + 255) >> 8)   // 391
#define EPB 4096                       // edges per block in binA/binB
#define NBX 12500                      // tobf16 blocks: N*128/4/256

typedef __attribute__((ext_vector_type(8))) short bf16x8;
typedef __attribute__((ext_vector_type(4))) float f32x4;

__device__ inline ushort f2bf(float f) {
    unsigned u = __float_as_uint(f);
    u += 0x7FFF + ((u >> 16) & 1);
    return (ushort)(u >> 16);
}
__device__ inline unsigned pk2(float lo, float hi) {
    return ((unsigned)f2bf(lo)) | (((unsigned)f2bf(hi)) << 16);
}

// unpack uint4 (8 bf16) and accumulate into a0[8]/a1[8] by relation bit (p>>20)
#define UNPACK_ACC(p, U)                                            \
    {                                                               \
        float f0 = __uint_as_float((U).x << 16);                    \
        float f1 = __uint_as_float((U).x & 0xFFFF0000u);            \
        float f2 = __uint_as_float((U).y << 16);                    \
        float f3 = __uint_as_float((U).y & 0xFFFF0000u);            \
        float f4 = __uint_as_float((U).z << 16);                    \
        float f5 = __uint_as_float((U).z & 0xFFFF0000u);            \
        float f6 = __uint_as_float((U).w << 16);                    \
        float f7 = __uint_as_float((U).w & 0xFFFF0000u);            \
        if ((p) >> 20) {                                            \
            a1[0] += f0; a1[1] += f1; a1[2] += f2; a1[3] += f3;     \
            a1[4] += f4; a1[5] += f5; a1[6] += f6; a1[7] += f7;     \
        } else {                                                    \
            a0[0] += f0; a0[1] += f1; a0[2] += f2; a0[3] += f3;     \
            a0[4] += f4; a0[5] += f5; a0[6] += f6; a0[7] += f7;     \
        }                                                           \
    }

// ---------------- merged: binA (bucket histogram) + prep (x->bf16, W stacks) ----------------
__global__ __launch_bounds__(256) void prepA_kernel(const int* __restrict__ dst,
                                                    int* __restrict__ bucketCnt,
                                                    int* __restrict__ blockHist, int E, int nblk,
                                                    const float* __restrict__ x, ushort* __restrict__ xb,
                                                    const float* __restrict__ basis0, const float* __restrict__ comp0,
                                                    const float* __restrict__ root0, ushort* __restrict__ Wt0,
                                                    const float* __restrict__ basis1, const float* __restrict__ comp1,
                                                    const float* __restrict__ root1, float* __restrict__ Wst1) {
    const int tid = threadIdx.x;
    if ((int)blockIdx.x < nblk) {
        __shared__ int h[NBUCK];
        for (int b = tid; b < NBUCK; b += 256) h[b] = 0;
        __syncthreads();
        const int e0 = blockIdx.x * EPB;
#pragma unroll
        for (int i = 0; i < EPB / 256; i++) {
            int e = e0 + i * 256 + tid;
            if (e < E) atomicAdd(&h[dst[e] >> BSHIFT], 1);
        }
        __syncthreads();
        const int row = blockIdx.x * NBUCK;
        for (int b = tid; b < NBUCK; b += 256) {
            int c = h[b];
            blockHist[row + b] = c;
            if (c) atomicAdd(&bucketCnt[b], c);
        }
        return;
    }
    const int bid = blockIdx.x - nblk;
    if (bid < NBX) {
        int i = (bid * 256 + tid) * 4;
        float4 v = *(const float4*)(x + i);
        uint2 p;
        p.x = pk2(v.x, v.y);
        p.y = pk2(v.z, v.w);
        *(uint2*)(xb + i) = p;
    } else if (bid < NBX + 192) {
        int idx = (bid - NBX) * 256 + tid;   // < 384*128
        int k = idx >> 7, o = idx & 127;
        float v;
        if (k < 256) {
            int r = k >> 7, i = k & 127;
            v = comp0[r * 2 + 0] * basis0[(size_t)(0 * 128 + i) * 128 + o]
              + comp0[r * 2 + 1] * basis0[(size_t)(1 * 128 + i) * 128 + o];
        } else {
            v = root0[(size_t)(k - 256) * 128 + o];
        }
        Wt0[(size_t)o * 384 + k] = f2bf(v);
    } else {
        int idx = (bid - NBX - 192) * 256 + tid;  // < 384*64
        int k = idx / 64, o = idx & 63;
        float v;
        if (k < 256) {
            int r = k >> 7, i = k & 127;
            v = comp1[r * 2 + 0] * basis1[(size_t)(0 * 128 + i) * 64 + o]
              + comp1[r * 2 + 1] * basis1[(size_t)(1 * 128 + i) * 64 + o];
        } else {
            v = root1[(size_t)(k - 256) * 64 + o];
        }
        Wst1[idx] = v;
    }
}

__global__ void bscan_kernel(const int* __restrict__ bucketCnt, int* __restrict__ bucketBase,
                             int* __restrict__ bucketCur, int* __restrict__ rowptr, int E) {
    __shared__ int s[512];
    int t = threadIdx.x;
    int v = (t < NBUCK) ? bucketCnt[t] : 0;
    s[t] = v;
    __syncthreads();
    for (int off = 1; off < 512; off <<= 1) {
        int u = (t >= off) ? s[t - off] : 0;
        __syncthreads();
        s[t] += u;
        __syncthreads();
    }
    if (t < NBUCK) {
        int excl = s[t] - v;
        bucketBase[t] = excl;
        bucketCur[t] = excl;
    }
    if (t == 0) rowptr[N_NODES] = E;
}

// binB: binned scatter; per-block counts come from blockHist (prepA) — no re-histogram
__global__ __launch_bounds__(256) void binB_kernel(const int* __restrict__ src,
                                                   const int* __restrict__ dst,
                                                   const int* __restrict__ etype,
                                                   const int* __restrict__ blockHist,
                                                   int* __restrict__ bucketCur,
                                                   int* __restrict__ tmp, int E) {
    __shared__ int hBase[NBUCK];
    __shared__ int hCur[NBUCK];
    const int tid = threadIdx.x;
    const int row = blockIdx.x * NBUCK;
    for (int b = tid; b < NBUCK; b += 256) {
        int c = blockHist[row + b];
        hBase[b] = c ? atomicAdd(&bucketCur[b], c) : 0;
        hCur[b] = 0;
    }
    __syncthreads();
    const int e0 = blockIdx.x * EPB;
#pragma unroll
    for (int i = 0; i < EPB / 256; i++) {
        int e = e0 + i * 256 + tid;
        if (e < E) {
            int d = dst[e];
            int b = d >> BSHIFT;
            int r = atomicAdd(&hCur[b], 1);
            tmp[hBase[b] + r] = src[e] | (etype[e] << 20) | ((d & 255) << 21);
        }
    }
}

// binC: per-bucket local counting sort by node; writes cnt, rowptr, adj
__global__ __launch_bounds__(256) void binC_kernel(const int* __restrict__ tmp,
                                                   const int* __restrict__ bucketBase,
                                                   const int* __restrict__ bucketCnt,
                                                   int* __restrict__ adj, int* __restrict__ cnt,
                                                   int* __restrict__ rowptr) {
    __shared__ int nc[512];
    __shared__ int nbase[256];
    __shared__ int ncur[256];
    __shared__ int sc[256];
    const int tid = threadIdx.x;
    const int b = blockIdx.x;
    const int base = bucketBase[b];
    const int m = bucketCnt[b];
    const int node0 = b << BSHIFT;
    const int nn = min(256, N_NODES - node0);

    nc[tid] = 0; nc[tid + 256] = 0; ncur[tid] = 0;
    __syncthreads();
    for (int i = tid; i < m; i += 256) {
        int v = tmp[base + i];
        atomicAdd(&nc[((v >> 21) & 255) * 2 + ((v >> 20) & 1)], 1);
    }
    __syncthreads();
    int tot = 0;
    if (tid < nn) {
        int c0 = nc[tid * 2], c1 = nc[tid * 2 + 1];
        cnt[(size_t)(node0 + tid) * 2] = c0;
        cnt[(size_t)(node0 + tid) * 2 + 1] = c1;
        tot = c0 + c1;
    }
    sc[tid] = tot;
    __syncthreads();
    for (int off = 1; off < 256; off <<= 1) {
        int u = (tid >= off) ? sc[tid - off] : 0;
        __syncthreads();
        sc[tid] += u;
        __syncthreads();
    }
    int excl = sc[tid] - tot;
    nbase[tid] = excl;
    if (tid < nn) rowptr[node0 + tid] = base + excl;
    __syncthreads();
    for (int i = tid; i < m; i += 256) {
        int v = tmp[base + i];
        int dl = (v >> 21) & 255;
        int pos = base + nbase[dl] + atomicAdd(&ncur[dl], 1);
        adj[pos] = v & 0x1FFFFF;
    }
}

// ---------------- gather0: one wave per node; 16 lanes x dwordx4 per edge-row ----------------
// lane = eg*16 + dl: edge-group eg handles edges i+eg; dim-group dl handles dims dl*8..dl*8+7
__global__ __launch_bounds__(256) void gather0_kernel(const int* __restrict__ rowptr,
                                                      const int* __restrict__ adj,
                                                      const int* __restrict__ cnt,
                                                      const ushort* __restrict__ xb,
                                                      ushort* __restrict__ A) {
    int g = blockIdx.x * blockDim.x + threadIdx.x;
    int n = g >> 6, lane = g & 63;
    if (n >= N_NODES) return;
    const int eg = lane >> 4;
    const int dl = lane & 15;
    float a0[8], a1[8];
#pragma unroll
    for (int k = 0; k < 8; k++) { a0[k] = 0.f; a1[k] = 0.f; }
    const int beg = rowptr[n], end = rowptr[n + 1];
    int i = beg;
    for (; i + 8 <= end; i += 8) {      // 8 edges per iteration, 2 dwordx4 loads in flight
        const int p0 = adj[i + eg];
        const int p1 = adj[i + 4 + eg];
        const uint4 u0 = *(const uint4*)(xb + (size_t)(p0 & 0xFFFFF) * 128 + dl * 8);
        const uint4 u1 = *(const uint4*)(xb + (size_t)(p1 & 0xFFFFF) * 128 + dl * 8);
        UNPACK_ACC(p0, u0);
        UNPACK_ACC(p1, u1);
    }
    if (i + 4 <= end) {
        const int p0 = adj[i + eg];
        const uint4 u0 = *(const uint4*)(xb + (size_t)(p0 & 0xFFFFF) * 128 + dl * 8);
        UNPACK_ACC(p0, u0);
        i += 4;
    }
    if (i < end) {
        const int ig = i + eg;
        if (ig < end) {
            const int p0 = adj[ig];
            const uint4 u0 = *(const uint4*)(xb + (size_t)(p0 & 0xFFFFF) * 128 + dl * 8);
            UNPACK_ACC(p0, u0);
        }
    }
    // reduce across the 4 edge-groups
#pragma unroll
    for (int k = 0; k < 8; k++) { a0[k] += __shfl_xor(a0[k], 16); a1[k] += __shfl_xor(a1[k], 16); }
#pragma unroll
    for (int k = 0; k < 8; k++) { a0[k] += __shfl_xor(a0[k], 32); a1[k] += __shfl_xor(a1[k], 32); }

    const int c0 = cnt[n * 2], c1 = cnt[n * 2 + 1];
    const float s0 = c0 > 0 ? 1.f / (float)c0 : 0.f;
    const float s1 = c1 > 0 ? 1.f / (float)c1 : 0.f;
    const float sc = (eg & 1) ? s1 : s0;
    float r[8];
#pragma unroll
    for (int k = 0; k < 8; k++) r[k] = ((eg & 1) ? a1[k] : a0[k]) * sc;
    if (eg < 2) {   // lanes 0-15 write rel0 row, 16-31 write rel1 row
        uint4 o;
        o.x = pk2(r[0], r[1]); o.y = pk2(r[2], r[3]);
        o.z = pk2(r[4], r[5]); o.w = pk2(r[6], r[7]);
        *(uint4*)(A + (size_t)n * 256 + eg * 128 + dl * 8) = o;
    }
}

// ---------------- gemm0 (MFMA bf16): x1 = relu([A | x] @ W + bias) ----------------
#define BM 128
#define BK 64
__global__ __launch_bounds__(256) void gemm0_kernel(const ushort* __restrict__ A,    // [N][256]
                                                    const ushort* __restrict__ xb,   // [N][128]
                                                    const ushort* __restrict__ Wt,   // [128][384]
                                                    const float* __restrict__ bias,
                                                    ushort* __restrict__ x1) {
    __shared__ ushort As[BM][BK + 8];
    __shared__ ushort Ws[128][BK + 8];
    const int tid = threadIdx.x;
    const int lane = tid & 63;
    const int w = tid >> 6;
    const int row0 = blockIdx.x * BM;

    f32x4 acc[2][8];
#pragma unroll
    for (int t = 0; t < 2; t++)
#pragma unroll
        for (int c = 0; c < 8; c++) acc[t][c] = (f32x4)0.f;

    for (int kc = 0; kc < 384; kc += BK) {
        __syncthreads();
#pragma unroll
        for (int q = 0; q < 4; q++) {
            const int seg = q * 256 + tid;       // 0..1023
            const int row = seg >> 3;            // 0..127
            const int sk = (seg & 7) * 8;
            const int gr = min(row0 + row, N_NODES - 1);
            uint4 val;
            if (kc < 256) val = *(const uint4*)&A[(size_t)gr * 256 + kc + sk];
            else          val = *(const uint4*)&xb[(size_t)gr * 128 + (kc - 256) + sk];
            *(uint4*)&As[row][sk] = val;
            *(uint4*)&Ws[row][sk] = *(const uint4*)&Wt[(size_t)row * 384 + kc + sk];
        }
        __syncthreads();
#pragma unroll
        for (int k2 = 0; k2 < 2; k2++) {
            const int kk = k2 * 32 + (lane >> 4) * 8;
            const bf16x8 af0 = *(const bf16x8*)&As[w * 32 + (lane & 15)][kk];
            const bf16x8 af1 = *(const bf16x8*)&As[w * 32 + 16 + (lane & 15)][kk];
            bf16x8 bf[8];
#pragma unroll
            for (int c = 0; c < 8; c++) bf[c] = *(const bf16x8*)&Ws[c * 16 + (lane & 15)][kk];
#pragma unroll
            for (int c = 0; c < 8; c++) {
                acc[0][c] = __builtin_amdgcn_mfma_f32_16x16x32_bf16(af0, bf[c], acc[0][c], 0, 0, 0);
                acc[1][c] = __builtin_amdgcn_mfma_f32_16x16x32_bf16(af1, bf[c], acc[1][c], 0, 0, 0);
            }
        }
    }

    // D layout: col = lane&15, row = (lane>>4)*4 + j
#pragma unroll
    for (int c = 0; c < 8; c++) {
        const int col = c * 16 + (lane & 15);
        const float b = bias[col];
#pragma unroll
        for (int t = 0; t < 2; t++) {
#pragma unroll
            for (int j = 0; j < 4; j++) {
                const int n = row0 + w * 32 + t * 16 + (lane >> 4) * 4 + j;
                if (n < N_NODES) x1[(size_t)n * 128 + col] = f2bf(fmaxf(acc[t][c][j] + b, 0.f));
            }
        }
    }
}

// ---------------- fused tail: gather1 + gemm2 + MLP head ----------------
__global__ __launch_bounds__(256) void tail_kernel(const int* __restrict__ ni,
                                                   const int* __restrict__ rowptr,
                                                   const int* __restrict__ adj,
                                                   const int* __restrict__ cnt,
                                                   const ushort* __restrict__ x1,
                                                   const float* __restrict__ Wst,   // [384][64]
                                                   const float* __restrict__ bias,
                                                   const float* __restrict__ W1, const float* __restrict__ b1,
                                                   const float* __restrict__ g1, const float* __restrict__ be1,
                                                   const float* __restrict__ W2, const float* __restrict__ b2,
                                                   const float* __restrict__ g2, const float* __restrict__ be2,
                                                   const float* __restrict__ W3, const float* __restrict__ b3,
                                                   float* __restrict__ outExpert, float* __restrict__ outProb,
                                                   int B) {
    __shared__ float As[16][384];
    __shared__ float x2s[16][64];
    const int tid = threadIdx.x;
    const int lane = tid & 63;
    const int w = tid >> 6;
    const int row0 = blockIdx.x * 16;
    const int eg = lane >> 4;
    const int dl = lane & 15;

    // ---- phase 1: gather A rows [agg0 | agg1 | x1[n]] into LDS (16 lanes x dwordx4 per edge) ----
    for (int j = 0; j < 4; j++) {
        const int r = w + j * 4;
        const int u = row0 + r;
        if (u < B) {
            const int n = ni[u];
            float a0[8], a1[8];
#pragma unroll
            for (int k = 0; k < 8; k++) { a0[k] = 0.f; a1[k] = 0.f; }
            const int beg = rowptr[n], end = rowptr[n + 1];
            int i = beg;
            for (; i + 8 <= end; i += 8) {
                const int p0 = adj[i + eg];
                const int p1 = adj[i + 4 + eg];
                const uint4 u0 = *(const uint4*)(x1 + (size_t)(p0 & 0xFFFFF) * 128 + dl * 8);
                const uint4 u1 = *(const uint4*)(x1 + (size_t)(p1 & 0xFFFFF) * 128 + dl * 8);
                UNPACK_ACC(p0, u0);
                UNPACK_ACC(p1, u1);
            }
            if (i + 4 <= end) {
                const int p0 = adj[i + eg];
                const uint4 u0 = *(const uint4*)(x1 + (size_t)(p0 & 0xFFFFF) * 128 + dl * 8);
                UNPACK_ACC(p0, u0);
                i += 4;
            }
            if (i < end) {
                const int ig = i + eg;
                if (ig < end) {
                    const int p0 = adj[ig];
                    const uint4 u0 = *(const uint4*)(x1 + (size_t)(p0 & 0xFFFFF) * 128 + dl * 8);
                    UNPACK_ACC(p0, u0);
                }
            }
#pragma unroll
            for (int k = 0; k < 8; k++) { a0[k] += __shfl_xor(a0[k], 16); a1[k] += __shfl_xor(a1[k], 16); }
#pragma unroll
            for (int k = 0; k < 8; k++) { a0[k] += __shfl_xor(a0[k], 32); a1[k] += __shfl_xor(a1[k], 32); }
            const int c0 = cnt[n * 2], c1 = cnt[n * 2 + 1];
            const float s0 = c0 > 0 ? 1.f / (float)c0 : 0.f;
            const float s1 = c1 > 0 ? 1.f / (float)c1 : 0.f;
            if (eg == 0) {
#pragma unroll
                for (int k = 0; k < 8; k++) As[r][dl * 8 + k] = a0[k] * s0;
            } else if (eg == 1) {
#pragma unroll
                for (int k = 0; k < 8; k++) As[r][128 + dl * 8 + k] = a1[k] * s1;
            } else if (eg == 2) {
                const uint4 ux = *(const uint4*)(x1 + (size_t)n * 128 + dl * 8);
                As[r][256 + dl * 8 + 0] = __uint_as_float(ux.x << 16);
                As[r][256 + dl * 8 + 1] = __uint_as_float(ux.x & 0xFFFF0000u);
                As[r][256 + dl * 8 + 2] = __uint_as_float(ux.y << 16);
                As[r][256 + dl * 8 + 3] = __uint_as_float(ux.y & 0xFFFF0000u);
                As[r][256 + dl * 8 + 4] = __uint_as_float(ux.z << 16);
                As[r][256 + dl * 8 + 5] = __uint_as_float(ux.z & 0xFFFF0000u);
                As[r][256 + dl * 8 + 6] = __uint_as_float(ux.w << 16);
                As[r][256 + dl * 8 + 7] = __uint_as_float(ux.w & 0xFFFF0000u);
            }
        }
    }
    __syncthreads();

    // ---- phase 2: gemm 16x384 @ 384x64 ----
    {
        const int o = tid & 63;
        const int q = tid >> 6;
        float acc[4] = {0.f, 0.f, 0.f, 0.f};
        for (int k = 0; k < 384; k += 4) {
            const float w0 = Wst[(k + 0) * 64 + o];
            const float w1_ = Wst[(k + 1) * 64 + o];
            const float w2_ = Wst[(k + 2) * 64 + o];
            const float w3_ = Wst[(k + 3) * 64 + o];
#pragma unroll
            for (int rr = 0; rr < 4; rr++) {
                const float4 a = *(const float4*)&As[q * 4 + rr][k];
                acc[rr] = fmaf(a.x, w0, acc[rr]);
                acc[rr] = fmaf(a.y, w1_, acc[rr]);
                acc[rr] = fmaf(a.z, w2_, acc[rr]);
                acc[rr] = fmaf(a.w, w3_, acc[rr]);
            }
        }
        const float bb = bias[o];
#pragma unroll
        for (int rr = 0; rr < 4; rr++) x2s[q * 4 + rr][o] = acc[rr] + bb;
    }
    __syncthreads();

    // ---- phase 3: MLP head, wave w handles rows w*4..w*4+3 ----
    for (int rr = 0; rr < 4; rr++) {
        const int r = w * 4 + rr;
        const int i = row0 + r;
        if (i >= B) continue;
        const int t = lane;
        const int tt = lane & 31;
        float e = x2s[r][t];
        outExpert[(size_t)i * 64 + t] = e;

        float y = b1[t];
#pragma unroll
        for (int k = 0; k < 64; k++) y = fmaf(__shfl(e, k), W1[k * 64 + t], y);
        float s = y;
        for (int off = 32; off; off >>= 1) s += __shfl_xor(s, off);
        float m = s * (1.f / 64.f);
        float d = y - m;
        float vs = d * d;
        for (int off = 32; off; off >>= 1) vs += __shfl_xor(vs, off);
        float h1 = fmaxf(fmaf(g1[t] * d, rsqrtf(vs * (1.f / 64.f) + 1e-5f), be1[t]), 0.f);

        float y2 = b2[tt];
#pragma unroll
        for (int k = 0; k < 64; k++) y2 = fmaf(__shfl(h1, k), W2[k * 32 + tt], y2);
        float s2 = y2;
        for (int off = 16; off; off >>= 1) s2 += __shfl_xor(s2, off);
        float m2 = s2 * (1.f / 32.f);
        float d2 = y2 - m2;
        float v2 = d2 * d2;
        for (int off = 16; off; off >>= 1) v2 += __shfl_xor(v2, off);
        float h2 = fmaxf(fmaf(g2[tt] * d2, rsqrtf(v2 * (1.f / 32.f) + 1e-5f), be2[tt]), 0.f);

        float p = h2 * W3[tt];
        for (int off = 16; off; off >>= 1) p += __shfl_xor(p, off);
        if (t == 0) outProb[i] = 1.f / (1.f + expf(-(p + b3[0])));
    }
}

extern "C" void kernel_launch(void* const* d_in, const int* in_sizes, int n_in,
                              void* d_out, int out_size, void* d_ws, size_t ws_size,
                              hipStream_t stream) {
    const int*   node_indices = (const int*)d_in[0];
    const int*   edge_index   = (const int*)d_in[1];
    const int*   edge_type    = (const int*)d_in[2];
    const float* x_feat       = (const float*)d_in[3];
    const float* basis0       = (const float*)d_in[4];
    const float* comp0        = (const float*)d_in[5];
    const float* root0        = (const float*)d_in[6];
    const float* bias0        = (const float*)d_in[7];
    const float* basis1       = (const float*)d_in[8];
    const float* comp1        = (const float*)d_in[9];
    const float* root1        = (const float*)d_in[10];
    const float* bias1        = (const float*)d_in[11];
    const float* W1 = (const float*)d_in[12];
    const float* b1 = (const float*)d_in[13];
    const float* g1 = (const float*)d_in[14];
    const float* be1 = (const float*)d_in[15];
    const float* W2 = (const float*)d_in[16];
    const float* b2 = (const float*)d_in[17];
    const float* g2 = (const float*)d_in[18];
    const float* be2 = (const float*)d_in[19];
    const float* W3 = (const float*)d_in[20];
    const float* b3 = (const float*)d_in[21];

    const int B = in_sizes[0];
    const int E = in_sizes[1] / 2;
    const int* src = edge_index;
    const int* dst = edge_index + E;
    const int nblk = (E + EPB - 1) / EPB;

    // ---- workspace carve-out (256B aligned) ----
    size_t off = 0;
    auto alloc = [&](size_t sz) { size_t o = off; off = (off + sz + 255) & ~(size_t)255; return o; };
    char* ws = (char*)d_ws;
    ushort* xb    = (ushort*)(ws + alloc((size_t)N_NODES * 128 * 2));
    ushort* Amat  = (ushort*)(ws + alloc((size_t)N_NODES * 256 * 2));
    ushort* x1b   = (ushort*)(ws + alloc((size_t)N_NODES * 128 * 2));
    int*   cnt    = (int*)  (ws + alloc((size_t)N_NODES * 2 * 4));
    int*   rowptr = (int*)  (ws + alloc((size_t)(N_NODES + 1) * 4));
    int*   adj    = (int*)  (ws + alloc((size_t)E * 4));
    int*   tmp    = (int*)  (ws + alloc((size_t)E * 4));
    int*   blockHist  = (int*)(ws + alloc((size_t)nblk * NBUCK * 4));
    int*   bucketCnt  = (int*)(ws + alloc((size_t)NBUCK * 4));
    int*   bucketBase = (int*)(ws + alloc((size_t)NBUCK * 4));
    int*   bucketCur  = (int*)(ws + alloc((size_t)NBUCK * 4));
    ushort* Wt0b  = (ushort*)(ws + alloc((size_t)128 * 384 * 2));
    float* Wst1   = (float*)(ws + alloc((size_t)384 * 64 * 4));

    float* outExpert = (float*)d_out;
    float* outProb   = (float*)d_out + (size_t)B * 64;

    hipMemsetAsync(bucketCnt, 0, (size_t)NBUCK * 4, stream);

    // ---- merged binA + prep ----
    prepA_kernel<<<nblk + NBX + 192 + 96, 256, 0, stream>>>(dst, bucketCnt, blockHist, E, nblk,
                                                            x_feat, xb, basis0, comp0, root0, Wt0b,
                                                            basis1, comp1, root1, Wst1);

    // ---- CSR build ----
    bscan_kernel<<<1, 512, 0, stream>>>(bucketCnt, bucketBase, bucketCur, rowptr, E);
    binB_kernel<<<nblk, 256, 0, stream>>>(src, dst, edge_type, blockHist, bucketCur, tmp, E);
    binC_kernel<<<NBUCK, 256, 0, stream>>>(tmp, bucketBase, bucketCnt, adj, cnt, rowptr);

    // ---- layer 0 ----
    gather0_kernel<<<(N_NODES * 64 + 255) / 256, 256, 0, stream>>>(rowptr, adj, cnt, xb, Amat);
    gemm0_kernel<<<(N_NODES + BM - 1) / BM, 256, 0, stream>>>(Amat, xb, Wt0b, bias0, x1b);

    // ---- layer 1 + head (fused) ----
    tail_kernel<<<(B + 15) / 16, 256, 0, stream>>>(node_indices, rowptr, adj, cnt, x1b,
                                                   Wst1, bias1,
                                                   W1, b1, g1, be1, W2, b2, g2, be2, W3, b3,
                                                   outExpert, outProb, B);
}